// Round 5
// baseline (324.136 us; speedup 1.0000x reference)
//
#include <hip/hip_runtime.h>
#include <stdint.h>

// GPUHausdorffLoss — R5: no memsets, no zero-dependencies, 6 launches.
//  K1 sobel_cand (2048 blk = 128 img-sides x 16 slices, 256 thr):
//     rows staged via LDS (1 float2 load + 2 sigmoids per thread-row),
//     threefry m once/px, per-slice 256-bin hist part (non-atomic store),
//     candidates (cbin>=252) staged in LDS -> per-slice segment + raw count.
//  K2 thresh (128 blk): sum 16 hist parts, suffix-scan -> exact T, r; flag
//     repair if T<252 or any slice overflow; zeroes repair counter itself.
//  K3 repair (2048 blk, early-exit): rebuilds candidates with bin>=T (rare).
//  K4 resolve (128 blk): emit cbin>T, fine 1024-bin radix in bin T, exact
//     (m desc, idx asc) tie rank; writes pts + count.
//  K5 haus (512 blk): per (img,dir,seg) partial max of min d^2 -> g_hpart.
//  K6 fin (1x64): reduce 8 partials/img, clip, mean, write out.

#define HH 512
#define WW 512
#define NPIX (HH * WW)
#define NSEL 1000
#define NBIN 256
#define CBIN_CUT 252u
#define SLICE_CAP 512
#define CAND2CAP 16384
#define STAGE2CAP 2048
#define ROWS_PER 32

#if __has_builtin(__builtin_amdgcn_alignbit)
__device__ __forceinline__ uint32_t rotl32(uint32_t x, int r) {
  return __builtin_amdgcn_alignbit(x, x, (32 - r) & 31);
}
#else
__device__ __forceinline__ uint32_t rotl32(uint32_t x, int r) {
  return (x << r) | (x >> (32 - r));
}
#endif

// JAX threefry2x32: 20 rounds, key schedule every 4.
__device__ __forceinline__ void tf2x32(uint32_t k0, uint32_t k1,
                                       uint32_t c0, uint32_t c1,
                                       uint32_t& o0, uint32_t& o1) {
  uint32_t ks2 = k0 ^ k1 ^ 0x1BD11BDAu;
  uint32_t x0 = c0 + k0, x1 = c1 + k1;
#define TF_R(r) { x0 += x1; x1 = rotl32(x1, (r)); x1 ^= x0; }
  TF_R(13) TF_R(15) TF_R(26) TF_R(6)
  x0 += k1;  x1 += ks2 + 1u;
  TF_R(17) TF_R(29) TF_R(16) TF_R(24)
  x0 += ks2; x1 += k0 + 2u;
  TF_R(13) TF_R(15) TF_R(26) TF_R(6)
  x0 += k0;  x1 += k1 + 3u;
  TF_R(17) TF_R(29) TF_R(16) TF_R(24)
  x0 += k1;  x1 += ks2 + 4u;
  TF_R(13) TF_R(15) TF_R(26) TF_R(6)
  x0 += ks2; x1 += k0 + 5u;
#undef TF_R
  o0 = x0; o1 = x1;
}

// Exact rank value of score = 2.0f + uniform(bits): bits(score) - bits(2.0f).
__device__ __forceinline__ uint32_t pixel_m(uint32_t k0, uint32_t k1, int p) {
  uint32_t b1, b2;
  tf2x32(k0, k1, 0u, (uint32_t)p, b1, b2);
  uint32_t bits = b1 ^ b2;
  float noise = __uint_as_float((bits >> 9) | 0x3F800000u) - 1.0f;
  float score = 2.0f + noise;
  return __float_as_uint(score) - 0x40000000u;  // 0 .. 0x400000 inclusive
}

__device__ __forceinline__ uint32_t cbin_of(uint32_t m) {
  uint32_t b = m >> 14;
  return b > 255u ? 255u : b;
}

__device__ __forceinline__ float sigf(float x) { return 1.0f / (1.0f + __expf(-x)); }

__device__ __forceinline__ float ldval(const float* __restrict__ img, int r, int c, bool isPred) {
  if (r < 0 || r > HH - 1 || c < 0 || c > WW - 1) return 0.0f;  // conv zero-pad (post-sigmoid)
  float v = img[(size_t)r * WW + c];
  return isPred ? sigf(v) : v;
}

__device__ __forceinline__ uint32_t pack_pt(uint32_t p) {
  return ((p >> 9) << 16) | (p & 511u);
}

// ---------------- K1 ----------------
__global__ __launch_bounds__(256) void sobel_cand(
    const float* __restrict__ pred, const float* __restrict__ tgt,
    int* __restrict__ g_histp, int* __restrict__ g_scnt,
    unsigned long long* __restrict__ g_cand) {
  const int bid = blockIdx.x;
  const int b = bid >> 4, s = bid & 15;
  const int r0 = s * ROWS_PER;
  const int t = threadIdx.x;
  const bool isPred = b < 64;
  const float* img = isPred ? pred + (size_t)b * NPIX : tgt + (size_t)(b - 64) * NPIX;

  __shared__ float rowbuf[2][WW + 2];  // buf[i] = sigmoided col i-1; halo zeros
  __shared__ int hist[NBIN];
  __shared__ unsigned long long stage[SLICE_CAP];
  __shared__ int s_cn;
  hist[t] = 0;
  if (t == 0) s_cn = 0;

  uint32_t k0, k1;
  tf2x32(0u, 1u, 0u, (uint32_t)b, k0, k1);

  const int c0 = 2 * t;
  // preamble: rows r0-1, r0, r0+1 into registers (scalar path, once per block)
  float a0 = ldval(img, r0 - 1, c0 - 1, isPred), a1 = ldval(img, r0 - 1, c0, isPred),
        a2 = ldval(img, r0 - 1, c0 + 1, isPred), a3 = ldval(img, r0 - 1, c0 + 2, isPred);
  float b0 = ldval(img, r0, c0 - 1, isPred), b1 = ldval(img, r0, c0, isPred),
        b2 = ldval(img, r0, c0 + 1, isPred), b3 = ldval(img, r0, c0 + 2, isPred);
  float d0 = ldval(img, r0 + 1, c0 - 1, isPred), d1 = ldval(img, r0 + 1, c0, isPred),
        d2 = ldval(img, r0 + 1, c0 + 1, isPred), d3 = ldval(img, r0 + 1, c0 + 2, isPred);
  __syncthreads();  // hist init + preamble done

  for (int rr = 0; rr < ROWS_PER; ++rr) {
    const int r = r0 + rr;
    const int p = r * WW + c0;
    float gx0 = (a2 - a0) + 2.0f * (b2 - b0) + (d2 - d0);
    float gy0 = (d0 - a0) + 2.0f * (d1 - a1) + (d2 - a2);
    float gx1 = (a3 - a1) + 2.0f * (b3 - b1) + (d3 - d1);
    float gy1 = (d1 - a1) + 2.0f * (d2 - a2) + (d3 - a3);
    bool v0 = (gx0 * gx0 + gy0 * gy0 + 1e-8f) > 0.01f;
    bool v1 = (gx1 * gx1 + gy1 * gy1 + 1e-8f) > 0.01f;
    uint32_t m0 = pixel_m(k0, k1, p);
    uint32_t m1 = pixel_m(k0, k1, p + 1);
    uint32_t bin0 = cbin_of(m0), bin1 = cbin_of(m1);
    if (v0) {
      atomicAdd(&hist[bin0], 1);
      if (bin0 >= CBIN_CUT) {
        int i = atomicAdd(&s_cn, 1);
        if (i < SLICE_CAP) stage[i] = ((unsigned long long)m0 << 32) | (uint32_t)p;
      }
    }
    if (v1) {
      atomicAdd(&hist[bin1], 1);
      if (bin1 >= CBIN_CUT) {
        int i = atomicAdd(&s_cn, 1);
        if (i < SLICE_CAP) stage[i] = ((unsigned long long)m1 << 32) | (uint32_t)(p + 1);
      }
    }
    if (rr < ROWS_PER - 1) {
      // stage row r+2 (sigmoid once per column via LDS)
      float* buf = rowbuf[rr & 1];
      const int rn = r + 2;
      __syncthreads();  // prior reads of this buffer (2 iters ago) done
      if (rn <= HH - 1) {
        const float2 vv = *(const float2*)(img + (size_t)rn * WW + c0);
        float s0 = vv.x, s1 = vv.y;
        if (isPred) { s0 = sigf(s0); s1 = sigf(s1); }
        buf[c0 + 1] = s0;
        buf[c0 + 2] = s1;
      } else {
        buf[c0 + 1] = 0.0f;
        buf[c0 + 2] = 0.0f;
      }
      if (t == 0) { buf[0] = 0.0f; buf[WW + 1] = 0.0f; }
      __syncthreads();
      a0 = b0; a1 = b1; a2 = b2; a3 = b3;
      b0 = d0; b1 = d1; b2 = d2; b3 = d3;
      d0 = buf[c0]; d1 = buf[c0 + 1]; d2 = buf[c0 + 2]; d3 = buf[c0 + 3];
    }
  }
  __syncthreads();

  // per-slice outputs (no global atomics, no zeroing needed)
  const int raw = s_cn;
  const int n = raw < SLICE_CAP ? raw : SLICE_CAP;
  for (int i = t; i < n; i += 256) g_cand[(size_t)bid * SLICE_CAP + i] = stage[i];
  if (t == 0) g_scnt[bid] = raw;
  g_histp[(size_t)bid * NBIN + t] = hist[t];
}

// ---------------- K2 ----------------
__global__ __launch_bounds__(256) void thresh_kernel(
    const int* __restrict__ g_histp, const int* __restrict__ g_scnt,
    int* __restrict__ g_candc2, int* __restrict__ g_params) {
  const int img = blockIdx.x;
  const int t = threadIdx.x;
  __shared__ int sfx[NBIN];
  __shared__ int s_ovf;
  int* params = g_params + img * 4;
  if (t == 0) { g_candc2[img] = 0; s_ovf = 0; }
  __syncthreads();
  int sum = 0;
  for (int s = 0; s < 16; ++s) sum += g_histp[(size_t)(img * 16 + s) * NBIN + t];
  sfx[t] = sum;
  if (t < 16 && g_scnt[img * 16 + t] > SLICE_CAP) atomicOr(&s_ovf, 1);
  __syncthreads();
  for (int o = 1; o < NBIN; o <<= 1) {  // inclusive suffix sum
    int v = (t + o < NBIN) ? sfx[t + o] : 0;
    __syncthreads();
    sfx[t] += v;
    __syncthreads();
  }
  const int cv = sfx[0];
  if (cv == 0) {
    if (t == 0) { params[0] = 2; params[1] = -1; params[2] = 0; params[3] = 0; }
    return;
  }
  const int need = cv < NSEL ? cv : NSEL;
  int nxt = (t + 1 < NBIN) ? sfx[t + 1] : 0;
  if (sfx[t] >= need && nxt < need) {  // exactly one t
    params[0] = 0;
    params[1] = t;                                        // threshold bin T
    params[2] = need - nxt;                               // r from bin T (>=1)
    params[3] = (t < (int)CBIN_CUT || s_ovf) ? 1 : 0;     // repair flag
  }
}

// ---------------- K3 repair (rare; early-exit) ----------------
__global__ __launch_bounds__(256) void repair_kernel(
    const float* __restrict__ pred, const float* __restrict__ tgt,
    const int* __restrict__ g_params, int* __restrict__ g_candc2,
    unsigned long long* __restrict__ g_cand2) {
  const int bid = blockIdx.x;
  const int b = bid >> 4, s = bid & 15;
  if (g_params[b * 4 + 0] != 0 || g_params[b * 4 + 3] == 0) return;
  const int t = threadIdx.x;
  const uint32_t T = (uint32_t)g_params[b * 4 + 1];
  const bool isPred = b < 64;
  const float* img = isPred ? pred + (size_t)b * NPIX : tgt + (size_t)(b - 64) * NPIX;
  __shared__ unsigned long long stage[STAGE2CAP];
  __shared__ int s_cn, s_base, s_ncopy;
  if (t == 0) s_cn = 0;
  __syncthreads();
  uint32_t k0, k1;
  tf2x32(0u, 1u, 0u, (uint32_t)b, k0, k1);
  const int r0 = s * ROWS_PER;
  const int c0 = 2 * t;
  float a0 = ldval(img, r0 - 1, c0 - 1, isPred), a1 = ldval(img, r0 - 1, c0, isPred),
        a2 = ldval(img, r0 - 1, c0 + 1, isPred), a3 = ldval(img, r0 - 1, c0 + 2, isPred);
  float b0 = ldval(img, r0, c0 - 1, isPred), b1 = ldval(img, r0, c0, isPred),
        b2 = ldval(img, r0, c0 + 1, isPred), b3 = ldval(img, r0, c0 + 2, isPred);
  float d0 = ldval(img, r0 + 1, c0 - 1, isPred), d1 = ldval(img, r0 + 1, c0, isPred),
        d2 = ldval(img, r0 + 1, c0 + 1, isPred), d3 = ldval(img, r0 + 1, c0 + 2, isPred);
  for (int rr = 0; rr < ROWS_PER; ++rr) {
    const int r = r0 + rr;
    const int p = r * WW + c0;
    float gx0 = (a2 - a0) + 2.0f * (b2 - b0) + (d2 - d0);
    float gy0 = (d0 - a0) + 2.0f * (d1 - a1) + (d2 - a2);
    float gx1 = (a3 - a1) + 2.0f * (b3 - b1) + (d3 - d1);
    float gy1 = (d1 - a1) + 2.0f * (d2 - a2) + (d3 - a3);
    bool v0 = (gx0 * gx0 + gy0 * gy0 + 1e-8f) > 0.01f;
    bool v1 = (gx1 * gx1 + gy1 * gy1 + 1e-8f) > 0.01f;
    uint32_t m0 = pixel_m(k0, k1, p);
    uint32_t m1 = pixel_m(k0, k1, p + 1);
    if (v0 && cbin_of(m0) >= T) {
      int i = atomicAdd(&s_cn, 1);
      if (i < STAGE2CAP) stage[i] = ((unsigned long long)m0 << 32) | (uint32_t)p;
    }
    if (v1 && cbin_of(m1) >= T) {
      int i = atomicAdd(&s_cn, 1);
      if (i < STAGE2CAP) stage[i] = ((unsigned long long)m1 << 32) | (uint32_t)(p + 1);
    }
    if (rr < ROWS_PER - 1) {
      a0 = b0; a1 = b1; a2 = b2; a3 = b3;
      b0 = d0; b1 = d1; b2 = d2; b3 = d3;
      d0 = ldval(img, r + 2, c0 - 1, isPred);
      d1 = ldval(img, r + 2, c0, isPred);
      d2 = ldval(img, r + 2, c0 + 1, isPred);
      d3 = ldval(img, r + 2, c0 + 2, isPred);
    }
  }
  __syncthreads();
  if (t == 0) {
    int n = s_cn < STAGE2CAP ? s_cn : STAGE2CAP;
    s_base = atomicAdd(&g_candc2[b], n);
    s_ncopy = n;
  }
  __syncthreads();
  for (int i = t; i < s_ncopy; i += 256) {
    int gi = s_base + i;
    if (gi < CAND2CAP) g_cand2[(size_t)b * CAND2CAP + gi] = stage[i];
  }
}

// ---------------- K4 resolve (1 block per image-side) ----------------
__global__ __launch_bounds__(256) void resolve_kernel(
    const int* __restrict__ g_params, const int* __restrict__ g_scnt,
    const unsigned long long* __restrict__ g_cand,
    const int* __restrict__ g_candc2, const unsigned long long* __restrict__ g_cand2,
    uint32_t* __restrict__ g_pts, int* __restrict__ g_counts) {
  const int img = blockIdx.x;
  const int t = threadIdx.x;
  const int mode = g_params[img * 4 + 0];
  if (mode == 2) {  // cv==0 -> center fallback
    if (t == 0) { g_pts[img * NSEL] = (256u << 16) | 256u; g_counts[img] = 1; }
    return;
  }
  const uint32_t T = (uint32_t)g_params[img * 4 + 1];
  const int r = g_params[img * 4 + 2];
  const int flag = g_params[img * 4 + 3];

  __shared__ const unsigned long long* segp[16];
  __shared__ int segc[16];
  __shared__ int s_nseg;
  __shared__ int fh[1024];
  __shared__ int aux[256];
  __shared__ unsigned long long ties[256];
  __shared__ int s_pos, s_nt, s_T2, s_r2;
  if (t == 0) {
    s_pos = 0; s_nt = 0;
    if (flag) {
      int nc = g_candc2[img]; if (nc > CAND2CAP) nc = CAND2CAP;
      segp[0] = g_cand2 + (size_t)img * CAND2CAP;
      segc[0] = nc;
      s_nseg = 1;
    } else {
      for (int s = 0; s < 16; ++s) {
        int c = g_scnt[img * 16 + s]; if (c > SLICE_CAP) c = SLICE_CAP;
        segp[s] = g_cand + (size_t)(img * 16 + s) * SLICE_CAP;
        segc[s] = c;
      }
      s_nseg = 16;
    }
  }
  for (int i = t; i < 1024; i += 256) fh[i] = 0;
  __syncthreads();
  const int nseg = s_nseg;
  const uint32_t baseM = T << 14;

  // pass 1: direct-emit cbin>T; fine-hist cbin==T
  for (int si = 0; si < nseg; ++si) {
    const unsigned long long* C = segp[si];
    const int nc = segc[si];
    for (int i = t; i < nc; i += 256) {
      unsigned long long e = C[i];
      uint32_t m = (uint32_t)(e >> 32), p = (uint32_t)e;
      uint32_t cb = cbin_of(m);
      if (cb > T) {
        int pos = atomicAdd(&s_pos, 1);
        g_pts[img * NSEL + pos] = pack_pt(p);
      } else if (cb == T) {
        uint32_t f = (m - baseM) >> 4; if (f > 1023u) f = 1023u;
        atomicAdd(&fh[f], 1);
      }
    }
  }
  __syncthreads();
  // suffix-scan fh[1024]
  {
    int base = 4 * t, s = 0;
    for (int j = 3; j >= 0; --j) { s += fh[base + j]; fh[base + j] = s; }
    aux[t] = s;
    __syncthreads();
    for (int o = 1; o < 256; o <<= 1) {
      int v = (t + o < 256) ? aux[t + o] : 0;
      __syncthreads();
      aux[t] += v;
      __syncthreads();
    }
    int add = (t < 255) ? aux[t + 1] : 0;
    for (int j = 0; j < 4; ++j) fh[base + j] += add;
    __syncthreads();
    for (int j = 0; j < 4; ++j) {
      int idx = base + j;
      int sv = fh[idx];
      int nx = (idx < 1023) ? fh[idx + 1] : 0;
      if (sv >= r && nx < r) { s_T2 = idx; s_r2 = r - nx; }
    }
  }
  __syncthreads();
  const int T2 = s_T2, r2 = s_r2;
  // pass 2: emit fine>T2; collect fine==T2 ties
  for (int si = 0; si < nseg; ++si) {
    const unsigned long long* C = segp[si];
    const int nc = segc[si];
    for (int i = t; i < nc; i += 256) {
      unsigned long long e = C[i];
      uint32_t m = (uint32_t)(e >> 32), p = (uint32_t)e;
      if (cbin_of(m) == T) {
        uint32_t f = (m - baseM) >> 4; if (f > 1023u) f = 1023u;
        if ((int)f > T2) {
          int pos = atomicAdd(&s_pos, 1);
          g_pts[img * NSEL + pos] = pack_pt(p);
        } else if ((int)f == T2) {
          int j = atomicAdd(&s_nt, 1);
          if (j < 256) ties[j] = e;
        }
      }
    }
  }
  __syncthreads();
  int nt = s_nt < 256 ? s_nt : 256;
  for (int i = t; i < nt; i += 256) {
    unsigned long long e = ties[i];
    uint32_t mi = (uint32_t)(e >> 32), pi = (uint32_t)e;
    int rank = 0;
    for (int j = 0; j < nt; ++j) {
      unsigned long long e2 = ties[j];
      uint32_t mj = (uint32_t)(e2 >> 32), pj = (uint32_t)e2;
      rank += (mj > mi) || (mj == mi && pj < pi);
    }
    if (rank < r2) {
      int pos = atomicAdd(&s_pos, 1);
      g_pts[img * NSEL + pos] = pack_pt(pi);
    }
  }
  __syncthreads();
  if (t == 0) g_counts[img] = s_pos;  // == min(cv,1000)
}

// ---------------- K5 ----------------
__global__ __launch_bounds__(256) void haus_kernel(
    const uint32_t* __restrict__ g_pts, const int* __restrict__ g_counts,
    float* __restrict__ g_hpart) {
  const int bid = blockIdx.x;
  const int img = bid >> 3;
  const int dir = (bid >> 2) & 1;
  const int seg = bid & 3;
  const int t = threadIdx.x;
  const int iOwn = dir ? 64 + img : img;
  const int iOth = dir ? img : 64 + img;
  const int nOwn = g_counts[iOwn];
  const int nOth = g_counts[iOth];
  __shared__ float2 o[NSEL];
  __shared__ float red[256];
  for (int i = t; i < nOth; i += 256) {
    uint32_t v = g_pts[iOth * NSEL + i];
    o[i] = make_float2((float)(v >> 16), (float)(v & 0xFFFFu));
  }
  __syncthreads();
  float best = 0.0f;  // d^2 >= 0
  const int lo = seg * 250;
  const int hi = min(nOwn, lo + 250);
  for (int i = lo + t; i < hi; i += 256) {
    uint32_t v = g_pts[iOwn * NSEL + i];
    float pr = (float)(v >> 16), pc = (float)(v & 0xFFFFu);
    float mn = 3.4e38f;
    for (int j = 0; j < nOth; ++j) {
      float dr = pr - o[j].x, dc = pc - o[j].y;
      mn = fminf(mn, dr * dr + dc * dc);
    }
    best = fmaxf(best, mn);
  }
  red[t] = best;
  __syncthreads();
  for (int st = 128; st > 0; st >>= 1) {
    if (t < st) red[t] = fmaxf(red[t], red[t + st]);
    __syncthreads();
  }
  if (t == 0) g_hpart[bid] = red[0];
}

// ---------------- K6 ----------------
__global__ __launch_bounds__(64) void fin_kernel(const float* __restrict__ g_hpart,
                                                 float* __restrict__ out) {
  const int t = threadIdx.x;  // one thread per image
  float mx = 0.0f;
  for (int j = 0; j < 8; ++j) mx = fmaxf(mx, g_hpart[t * 8 + j]);
  float diag = sqrtf((float)(HH * HH + WW * WW));
  float hd = sqrtf(fmaxf(mx, 0.0f)) / diag;
  hd = fminf(fmaxf(hd, 0.0f), 0.1f);
  float s = hd;
  for (int o = 32; o > 0; o >>= 1) s += __shfl_down(s, o);
  if (t == 0) out[0] = s * 0.015625f;
}

// ---------------- workspace layout (bytes) — nothing needs pre-zeroing ----
#define WS_HISTP  0u                          // 2048*256*4 = 2097152
#define WS_SCNT   2097152u                    // 2048*4 = 8192
#define WS_PARAMS (WS_SCNT + 8192u)           // 128*4*4 = 2048
#define WS_CANDC2 (WS_PARAMS + 2048u)         // 512
#define WS_COUNTS (WS_CANDC2 + 512u)          // 512
#define WS_HPART  (WS_COUNTS + 512u)          // 512*4 = 2048
#define WS_PTS    (WS_HPART + 2048u)          // 128*1000*4 = 512000
#define WS_CAND   (WS_PTS + 512000u)          // 2048*512*8 = 8388608
#define WS_CAND2  (WS_CAND + 8388608u)        // 128*16384*8 = 16777216 (~27.8 MB total)

extern "C" void kernel_launch(void* const* d_in, const int* in_sizes, int n_in,
                              void* d_out, int out_size, void* d_ws, size_t ws_size,
                              hipStream_t stream) {
  const float* pred = (const float*)d_in[0];
  const float* tgt = (const float*)d_in[1];
  float* out = (float*)d_out;
  char* ws = (char*)d_ws;
  int* g_histp = (int*)(ws + WS_HISTP);
  int* g_scnt = (int*)(ws + WS_SCNT);
  int* g_params = (int*)(ws + WS_PARAMS);
  int* g_candc2 = (int*)(ws + WS_CANDC2);
  int* g_counts = (int*)(ws + WS_COUNTS);
  float* g_hpart = (float*)(ws + WS_HPART);
  uint32_t* g_pts = (uint32_t*)(ws + WS_PTS);
  unsigned long long* g_cand = (unsigned long long*)(ws + WS_CAND);
  unsigned long long* g_cand2 = (unsigned long long*)(ws + WS_CAND2);

  sobel_cand<<<2048, 256, 0, stream>>>(pred, tgt, g_histp, g_scnt, g_cand);
  thresh_kernel<<<128, 256, 0, stream>>>(g_histp, g_scnt, g_candc2, g_params);
  repair_kernel<<<2048, 256, 0, stream>>>(pred, tgt, g_params, g_candc2, g_cand2);
  resolve_kernel<<<128, 256, 0, stream>>>(g_params, g_scnt, g_cand, g_candc2, g_cand2,
                                          g_pts, g_counts);
  haus_kernel<<<512, 256, 0, stream>>>(g_pts, g_counts, g_hpart);
  fin_kernel<<<1, 64, 0, stream>>>(g_hpart, out);
}

// Round 6
// 321.419 us; speedup vs baseline: 1.0085x; 1.0085x over previous
//
#include <hip/hip_runtime.h>
#include <stdint.h>

// GPUHausdorffLoss — R6: 4 launches, ~5.8 MB workspace (poison-cost theory),
// lean K1 (no hist, no LDS staging).
//  K1 sobel_cand (2048 blk = 128 img-sides x 16 slices): Sobel valid + threefry m
//     once/px; stage (m,p) with m >= 253<<14 into per-slice segment (no global
//     atomics); per-slice (valid_cnt, cand_cnt) written non-atomically.
//  K2 resolve (128 blk, 1/img): sums slice counters -> cv, need; fast path:
//     coarse-256/fine-1024 radix select + exact (m desc, idx asc) ties over the
//     staged candidates. Slow path (cand shortfall/overflow — statistically
//     never, kept for exactness): rebuilds candidates by rescanning the image
//     inside this block. Center fallback for cv==0. Writes pts + count.
//  K3 haus (512 blk): per (img,dir,seg) partial max of min d^2 -> g_hpart.
//  K4 fin (1x64): reduce 8 partials/img, clip, mean -> out[0].

#define HH 512
#define WW 512
#define NPIX (HH * WW)
#define NSEL 1000
#define SLICE_CAP 320
#define CUTM (253u << 14)   // candidates: m >= CUTM (top 3 coarse bins)
#define ROWS_PER 32

#if __has_builtin(__builtin_amdgcn_alignbit)
__device__ __forceinline__ uint32_t rotl32(uint32_t x, int r) {
  return __builtin_amdgcn_alignbit(x, x, (32 - r) & 31);
}
#else
__device__ __forceinline__ uint32_t rotl32(uint32_t x, int r) {
  return (x << r) | (x >> (32 - r));
}
#endif

// JAX threefry2x32: 20 rounds, key schedule every 4.
__device__ __forceinline__ void tf2x32(uint32_t k0, uint32_t k1,
                                       uint32_t c0, uint32_t c1,
                                       uint32_t& o0, uint32_t& o1) {
  uint32_t ks2 = k0 ^ k1 ^ 0x1BD11BDAu;
  uint32_t x0 = c0 + k0, x1 = c1 + k1;
#define TF_R(r) { x0 += x1; x1 = rotl32(x1, (r)); x1 ^= x0; }
  TF_R(13) TF_R(15) TF_R(26) TF_R(6)
  x0 += k1;  x1 += ks2 + 1u;
  TF_R(17) TF_R(29) TF_R(16) TF_R(24)
  x0 += ks2; x1 += k0 + 2u;
  TF_R(13) TF_R(15) TF_R(26) TF_R(6)
  x0 += k0;  x1 += k1 + 3u;
  TF_R(17) TF_R(29) TF_R(16) TF_R(24)
  x0 += k1;  x1 += ks2 + 4u;
  TF_R(13) TF_R(15) TF_R(26) TF_R(6)
  x0 += ks2; x1 += k0 + 5u;
#undef TF_R
  o0 = x0; o1 = x1;
}

// Exact rank value of score = 2.0f + uniform(bits): bits(score) - bits(2.0f).
__device__ __forceinline__ uint32_t pixel_m(uint32_t k0, uint32_t k1, int p) {
  uint32_t b1, b2;
  tf2x32(k0, k1, 0u, (uint32_t)p, b1, b2);
  uint32_t bits = b1 ^ b2;
  float noise = __uint_as_float((bits >> 9) | 0x3F800000u) - 1.0f;
  float score = 2.0f + noise;
  return __float_as_uint(score) - 0x40000000u;  // 0 .. 0x400000 inclusive
}

__device__ __forceinline__ float sigf(float x) { return 1.0f / (1.0f + __expf(-x)); }

__device__ __forceinline__ float ldval(const float* __restrict__ img, int r, int c, bool isPred) {
  if (r < 0 || r > HH - 1 || c < 0 || c > WW - 1) return 0.0f;  // conv zero-pad (post-sigmoid)
  float v = img[(size_t)r * WW + c];
  return isPred ? sigf(v) : v;
}

__device__ __forceinline__ uint32_t pack_pt(uint32_t p) {
  return ((p >> 9) << 16) | (p & 511u);
}

// ---------------- K1 ----------------
__global__ __launch_bounds__(256) void sobel_cand(
    const float* __restrict__ pred, const float* __restrict__ tgt,
    int2* __restrict__ g_scnt, unsigned long long* __restrict__ g_cand) {
  const int bid = blockIdx.x;
  const int b = bid >> 4, s = bid & 15;
  const int r0 = s * ROWS_PER;
  const int t = threadIdx.x;
  const bool isPred = b < 64;
  const float* img = isPred ? pred + (size_t)b * NPIX : tgt + (size_t)(b - 64) * NPIX;

  __shared__ unsigned long long stage[SLICE_CAP];
  __shared__ int s_cn, s_cv;
  if (t == 0) { s_cn = 0; s_cv = 0; }

  uint32_t k0, k1;
  tf2x32(0u, 1u, 0u, (uint32_t)b, k0, k1);

  const int c0 = 2 * t;
  float a0 = ldval(img, r0 - 1, c0 - 1, isPred), a1 = ldval(img, r0 - 1, c0, isPred),
        a2 = ldval(img, r0 - 1, c0 + 1, isPred), a3 = ldval(img, r0 - 1, c0 + 2, isPred);
  float b0 = ldval(img, r0, c0 - 1, isPred), b1 = ldval(img, r0, c0, isPred),
        b2 = ldval(img, r0, c0 + 1, isPred), b3 = ldval(img, r0, c0 + 2, isPred);
  float d0 = ldval(img, r0 + 1, c0 - 1, isPred), d1 = ldval(img, r0 + 1, c0, isPred),
        d2 = ldval(img, r0 + 1, c0 + 1, isPred), d3 = ldval(img, r0 + 1, c0 + 2, isPred);
  __syncthreads();

  int myv = 0;
  int p = r0 * WW + c0;
#pragma unroll 2
  for (int rr = 0; rr < ROWS_PER; ++rr) {
    float gx0 = (a2 - a0) + 2.0f * (b2 - b0) + (d2 - d0);
    float gy0 = (d0 - a0) + 2.0f * (d1 - a1) + (d2 - a2);
    float gx1 = (a3 - a1) + 2.0f * (b3 - b1) + (d3 - d1);
    float gy1 = (d1 - a1) + 2.0f * (d2 - a2) + (d3 - a3);
    bool v0 = (gx0 * gx0 + gy0 * gy0 + 1e-8f) > 0.01f;  // sqrt(x)>0.1 <=> x>0.01
    bool v1 = (gx1 * gx1 + gy1 * gy1 + 1e-8f) > 0.01f;
    uint32_t m0 = pixel_m(k0, k1, p);
    uint32_t m1 = pixel_m(k0, k1, p + 1);
    myv += (int)v0 + (int)v1;
    if (v0 && m0 >= CUTM) {
      int i = atomicAdd(&s_cn, 1);
      if (i < SLICE_CAP) stage[i] = ((unsigned long long)m0 << 32) | (uint32_t)p;
    }
    if (v1 && m1 >= CUTM) {
      int i = atomicAdd(&s_cn, 1);
      if (i < SLICE_CAP) stage[i] = ((unsigned long long)m1 << 32) | (uint32_t)(p + 1);
    }
    if (rr < ROWS_PER - 1) {
      const int rn = r0 + rr + 2;
      a0 = b0; a1 = b1; a2 = b2; a3 = b3;
      b0 = d0; b1 = d1; b2 = d2; b3 = d3;
      d0 = ldval(img, rn, c0 - 1, isPred);
      d1 = ldval(img, rn, c0, isPred);
      d2 = ldval(img, rn, c0 + 1, isPred);
      d3 = ldval(img, rn, c0 + 2, isPred);
    }
    p += WW;
  }
  // wave-level valid-count reduce, 4 LDS atomics per block
  for (int o = 32; o > 0; o >>= 1) myv += __shfl_down(myv, o);
  if ((t & 63) == 0) atomicAdd(&s_cv, myv);
  __syncthreads();

  const int raw = s_cn;
  const int n = raw < SLICE_CAP ? raw : SLICE_CAP;
  for (int i = t; i < n; i += 256) g_cand[(size_t)bid * SLICE_CAP + i] = stage[i];
  if (t == 0) g_scnt[bid] = make_int2(s_cv, raw);
}

// ---------------- K2 resolve (1 block per image-side) ----------------
__global__ __launch_bounds__(256) void resolve_kernel(
    const float* __restrict__ pred, const float* __restrict__ tgt,
    const int2* __restrict__ g_scnt, unsigned long long* __restrict__ g_cand,
    uint32_t* __restrict__ g_pts, int* __restrict__ g_counts) {
  const int img = blockIdx.x;
  const int t = threadIdx.x;

  __shared__ int segc[16];
  __shared__ int s_info[4];  // cv, cnt_hi_sum, ovf, ncand_rebuilt
  __shared__ int ch[256];
  __shared__ int fh[1024];
  __shared__ int aux[256];
  __shared__ unsigned long long ties[256];
  __shared__ int s_pos, s_nt, s_T1, s_r1, s_T2, s_r2;

  if (t == 0) {
    int cv = 0, hi = 0, ovf = 0;
    for (int s = 0; s < 16; ++s) {
      int2 v = g_scnt[img * 16 + s];
      cv += v.x;
      hi += v.y;
      segc[s] = v.y < SLICE_CAP ? v.y : SLICE_CAP;
      if (v.y > SLICE_CAP) ovf = 1;
    }
    s_info[0] = cv; s_info[1] = hi; s_info[2] = ovf;
    s_pos = 0; s_nt = 0;
  }
  __syncthreads();
  const int cv = s_info[0];
  if (cv == 0) {  // center fallback
    if (t == 0) { g_pts[img * NSEL] = (256u << 16) | 256u; g_counts[img] = 1; }
    return;
  }
  const int need = cv < NSEL ? cv : NSEL;
  bool slow = (s_info[2] != 0) || (s_info[1] < need);

  unsigned long long* C = g_cand + (size_t)img * 16 * SLICE_CAP;
  int ncand;

  if (slow) {
    // ---- exact rebuild (statistically never taken): rescan whole image ----
    const bool isPred = img < 64;
    const float* im = isPred ? pred + (size_t)img * NPIX : tgt + (size_t)(img - 64) * NPIX;
    uint32_t k0, k1;
    tf2x32(0u, 1u, 0u, (uint32_t)img, k0, k1);
    // pass A: coarse hist over ALL valid px
    ch[t] = 0;
    __syncthreads();
    for (int p = t; p < NPIX; p += 256) {
      int r = p >> 9, c = p & 511;
      float gx = (ldval(im, r - 1, c + 1, isPred) - ldval(im, r - 1, c - 1, isPred)) +
                 2.0f * (ldval(im, r, c + 1, isPred) - ldval(im, r, c - 1, isPred)) +
                 (ldval(im, r + 1, c + 1, isPred) - ldval(im, r + 1, c - 1, isPred));
      float gy = (ldval(im, r + 1, c - 1, isPred) - ldval(im, r - 1, c - 1, isPred)) +
                 2.0f * (ldval(im, r + 1, c, isPred) - ldval(im, r - 1, c, isPred)) +
                 (ldval(im, r + 1, c + 1, isPred) - ldval(im, r - 1, c + 1, isPred));
      if ((gx * gx + gy * gy + 1e-8f) > 0.01f) {
        uint32_t m = pixel_m(k0, k1, p);
        uint32_t cb = m >> 14; if (cb > 255u) cb = 255u;
        atomicAdd(&ch[cb], 1);
      }
    }
    __syncthreads();
    // suffix-scan ch -> coarse threshold Tc with suffix >= need
    {
      aux[t] = ch[t];
      __syncthreads();
      for (int o = 1; o < 256; o <<= 1) {
        int v = (t + o < 256) ? aux[t + o] : 0;
        __syncthreads();
        aux[t] += v;
        __syncthreads();
      }
      int nx = (t + 1 < 256) ? aux[t + 1] : 0;
      if (aux[t] >= need && nx < need) s_T1 = t;
      __syncthreads();
    }
    const uint32_t Tc = (uint32_t)s_T1;
    if (t == 0) s_info[3] = 0;
    __syncthreads();
    // pass B: stage all valid px with coarse bin >= Tc (fits 16*SLICE_CAP=5120)
    for (int p = t; p < NPIX; p += 256) {
      int r = p >> 9, c = p & 511;
      float gx = (ldval(im, r - 1, c + 1, isPred) - ldval(im, r - 1, c - 1, isPred)) +
                 2.0f * (ldval(im, r, c + 1, isPred) - ldval(im, r, c - 1, isPred)) +
                 (ldval(im, r + 1, c + 1, isPred) - ldval(im, r + 1, c - 1, isPred)) ;
      float gy = (ldval(im, r + 1, c - 1, isPred) - ldval(im, r - 1, c - 1, isPred)) +
                 2.0f * (ldval(im, r + 1, c, isPred) - ldval(im, r - 1, c, isPred)) +
                 (ldval(im, r + 1, c + 1, isPred) - ldval(im, r - 1, c + 1, isPred));
      if ((gx * gx + gy * gy + 1e-8f) > 0.01f) {
        uint32_t m = pixel_m(k0, k1, p);
        uint32_t cb = m >> 14; if (cb > 255u) cb = 255u;
        if (cb >= Tc) {
          int i = atomicAdd(&s_info[3], 1);
          if (i < 16 * SLICE_CAP) C[i] = ((unsigned long long)m << 32) | (uint32_t)p;
        }
      }
    }
    __syncthreads();
    ncand = s_info[3] < 16 * SLICE_CAP ? s_info[3] : 16 * SLICE_CAP;
    // compact segment table: one segment
    if (t == 0) { segc[0] = ncand; for (int s = 1; s < 16; ++s) segc[s] = 0; }
    __syncthreads();
  }

  // ---- selection over candidate segments ----
  // coarse 256-bin hist
  ch[t] = 0;
  for (int i = t; i < 1024; i += 256) fh[i] = 0;
  __syncthreads();
  for (int s = 0; s < 16; ++s) {
    const unsigned long long* seg = C + (size_t)s * SLICE_CAP;
    for (int i = t; i < segc[s]; i += 256) {
      uint32_t m = (uint32_t)(seg[i] >> 32);
      uint32_t cb = m >> 14; if (cb > 255u) cb = 255u;
      atomicAdd(&ch[cb], 1);
    }
  }
  __syncthreads();
  {
    aux[t] = ch[t];
    __syncthreads();
    for (int o = 1; o < 256; o <<= 1) {
      int v = (t + o < 256) ? aux[t + o] : 0;
      __syncthreads();
      aux[t] += v;
      __syncthreads();
    }
    int nx = (t + 1 < 256) ? aux[t + 1] : 0;
    if (aux[t] >= need && nx < need) { s_T1 = t; s_r1 = need - nx; }
    __syncthreads();
  }
  const uint32_t T1 = (uint32_t)s_T1;
  const int r1 = s_r1;
  const uint32_t baseM = T1 << 14;

  // pass 1: emit coarse>T1, fine-hist coarse==T1
  for (int s = 0; s < 16; ++s) {
    const unsigned long long* seg = C + (size_t)s * SLICE_CAP;
    for (int i = t; i < segc[s]; i += 256) {
      unsigned long long e = seg[i];
      uint32_t m = (uint32_t)(e >> 32), p = (uint32_t)e;
      uint32_t cb = m >> 14; if (cb > 255u) cb = 255u;
      if (cb > T1) {
        int pos = atomicAdd(&s_pos, 1);
        g_pts[img * NSEL + pos] = pack_pt(p);
      } else if (cb == T1) {
        uint32_t f = (m - baseM) >> 4; if (f > 1023u) f = 1023u;
        atomicAdd(&fh[f], 1);
      }
    }
  }
  __syncthreads();
  // suffix-scan fh[1024] -> T2, r2
  {
    int base = 4 * t, sv = 0;
    for (int j = 3; j >= 0; --j) { sv += fh[base + j]; fh[base + j] = sv; }
    aux[t] = sv;
    __syncthreads();
    for (int o = 1; o < 256; o <<= 1) {
      int v = (t + o < 256) ? aux[t + o] : 0;
      __syncthreads();
      aux[t] += v;
      __syncthreads();
    }
    int add = (t < 255) ? aux[t + 1] : 0;
    for (int j = 0; j < 4; ++j) fh[base + j] += add;
    __syncthreads();
    for (int j = 0; j < 4; ++j) {
      int idx = base + j;
      int sfx = fh[idx];
      int nx = (idx < 1023) ? fh[idx + 1] : 0;
      if (sfx >= r1 && nx < r1) { s_T2 = idx; s_r2 = r1 - nx; }
    }
    __syncthreads();
  }
  const int T2 = s_T2, r2 = s_r2;
  // pass 2: emit fine>T2; collect fine==T2 ties
  for (int s = 0; s < 16; ++s) {
    const unsigned long long* seg = C + (size_t)s * SLICE_CAP;
    for (int i = t; i < segc[s]; i += 256) {
      unsigned long long e = seg[i];
      uint32_t m = (uint32_t)(e >> 32), p = (uint32_t)e;
      uint32_t cb = m >> 14; if (cb > 255u) cb = 255u;
      if (cb == T1) {
        uint32_t f = (m - baseM) >> 4; if (f > 1023u) f = 1023u;
        if ((int)f > T2) {
          int pos = atomicAdd(&s_pos, 1);
          g_pts[img * NSEL + pos] = pack_pt(p);
        } else if ((int)f == T2) {
          int j = atomicAdd(&s_nt, 1);
          if (j < 256) ties[j] = e;
        }
      }
    }
  }
  __syncthreads();
  int nt = s_nt < 256 ? s_nt : 256;
  for (int i = t; i < nt; i += 256) {
    unsigned long long e = ties[i];
    uint32_t mi = (uint32_t)(e >> 32), pi = (uint32_t)e;
    int rank = 0;
    for (int j = 0; j < nt; ++j) {
      unsigned long long e2 = ties[j];
      uint32_t mj = (uint32_t)(e2 >> 32), pj = (uint32_t)e2;
      rank += (mj > mi) || (mj == mi && pj < pi);
    }
    if (rank < r2) {
      int pos = atomicAdd(&s_pos, 1);
      g_pts[img * NSEL + pos] = pack_pt(pi);
    }
  }
  __syncthreads();
  if (t == 0) g_counts[img] = s_pos;  // == need
}

// ---------------- K3 ----------------
__global__ __launch_bounds__(256) void haus_kernel(
    const uint32_t* __restrict__ g_pts, const int* __restrict__ g_counts,
    float* __restrict__ g_hpart) {
  const int bid = blockIdx.x;
  const int img = bid >> 3;
  const int dir = (bid >> 2) & 1;
  const int seg = bid & 3;
  const int t = threadIdx.x;
  const int iOwn = dir ? 64 + img : img;
  const int iOth = dir ? img : 64 + img;
  const int nOwn = g_counts[iOwn];
  const int nOth = g_counts[iOth];
  __shared__ float2 o[NSEL];
  __shared__ float red[256];
  for (int i = t; i < nOth; i += 256) {
    uint32_t v = g_pts[iOth * NSEL + i];
    o[i] = make_float2((float)(v >> 16), (float)(v & 0xFFFFu));
  }
  __syncthreads();
  float best = 0.0f;
  const int lo = seg * 250;
  const int hi = min(nOwn, lo + 250);
  for (int i = lo + t; i < hi; i += 256) {
    uint32_t v = g_pts[iOwn * NSEL + i];
    float pr = (float)(v >> 16), pc = (float)(v & 0xFFFFu);
    float mn = 3.4e38f;
    for (int j = 0; j < nOth; ++j) {
      float dr = pr - o[j].x, dc = pc - o[j].y;
      mn = fminf(mn, dr * dr + dc * dc);
    }
    best = fmaxf(best, mn);
  }
  red[t] = best;
  __syncthreads();
  for (int st = 128; st > 0; st >>= 1) {
    if (t < st) red[t] = fmaxf(red[t], red[t + st]);
    __syncthreads();
  }
  if (t == 0) g_hpart[bid] = red[0];
}

// ---------------- K4 ----------------
__global__ __launch_bounds__(64) void fin_kernel(const float* __restrict__ g_hpart,
                                                 float* __restrict__ out) {
  const int t = threadIdx.x;  // one thread per image
  float mx = 0.0f;
  for (int j = 0; j < 8; ++j) mx = fmaxf(mx, g_hpart[t * 8 + j]);
  float diag = sqrtf((float)(HH * HH + WW * WW));
  float hd = sqrtf(fmaxf(mx, 0.0f)) / diag;
  hd = fminf(fmaxf(hd, 0.0f), 0.1f);
  float s = hd;
  for (int o = 32; o > 0; o >>= 1) s += __shfl_down(s, o);
  if (t == 0) out[0] = s * 0.015625f;
}

// ---------------- workspace layout (bytes) — nothing pre-zeroed ----------
#define WS_SCNT   0u                          // 2048*8 = 16384
#define WS_COUNTS 16384u                      // 512
#define WS_HPART  (WS_COUNTS + 512u)          // 2048
#define WS_PTS    (WS_HPART + 2048u)          // 512000
#define WS_CAND   (WS_PTS + 512000u)          // 2048*320*8 = 5242880  (~5.5 MB total)

extern "C" void kernel_launch(void* const* d_in, const int* in_sizes, int n_in,
                              void* d_out, int out_size, void* d_ws, size_t ws_size,
                              hipStream_t stream) {
  const float* pred = (const float*)d_in[0];
  const float* tgt = (const float*)d_in[1];
  float* out = (float*)d_out;
  char* ws = (char*)d_ws;
  int2* g_scnt = (int2*)(ws + WS_SCNT);
  int* g_counts = (int*)(ws + WS_COUNTS);
  float* g_hpart = (float*)(ws + WS_HPART);
  uint32_t* g_pts = (uint32_t*)(ws + WS_PTS);
  unsigned long long* g_cand = (unsigned long long*)(ws + WS_CAND);

  sobel_cand<<<2048, 256, 0, stream>>>(pred, tgt, g_scnt, g_cand);
  resolve_kernel<<<128, 256, 0, stream>>>(pred, tgt, g_scnt, g_cand, g_pts, g_counts);
  haus_kernel<<<512, 256, 0, stream>>>(g_pts, g_counts, g_hpart);
  fin_kernel<<<1, 64, 0, stream>>>(g_hpart, out);
}

// Round 7
// 303.023 us; speedup vs baseline: 1.0697x; 1.0607x over previous
//
#include <hip/hip_runtime.h>
#include <stdint.h>

// GPUHausdorffLoss — R7: wave-spans-full-row K1 (no per-lane bounds checks, no
// hot-loop syncs, shuffle halos, 1.25 sigmoid/px), 4 launches, ~5.8 MB ws.
//  K1 sobel_cand (2048 blk = 128 img-sides x 16 slices; wave w of 4 owns rows
//     [slice*32 + 8w, +8), lane owns 8 cols): Sobel valid + threefry m once/px;
//     stage (m,p) with m >= 253<<14 per-slice; per-slice (cv, raw) counters.
//  K2 resolve (128 blk, 1/img): coarse-256/fine-1024 radix select + exact
//     (m desc, idx asc) ties over staged candidates; exact slow-path rebuild on
//     shortfall/overflow (statistically never); center fallback cv==0.
//  K3 haus (512 blk): per (img,dir,seg) partial max of min d^2 -> g_hpart.
//  K4 fin (1x64): reduce 8 partials/img, clip, mean -> out[0].

#define HH 512
#define WW 512
#define NPIX (HH * WW)
#define NSEL 1000
#define SLICE_CAP 320
#define CUTM (253u << 14)   // candidates: m >= CUTM (top 3 of 256 coarse bins)
#define ROWS_PER 32

#if __has_builtin(__builtin_amdgcn_alignbit)
__device__ __forceinline__ uint32_t rotl32(uint32_t x, int r) {
  return __builtin_amdgcn_alignbit(x, x, (32 - r) & 31);
}
#else
__device__ __forceinline__ uint32_t rotl32(uint32_t x, int r) {
  return (x << r) | (x >> (32 - r));
}
#endif

// JAX threefry2x32: 20 rounds, key schedule every 4.
__device__ __forceinline__ void tf2x32(uint32_t k0, uint32_t k1,
                                       uint32_t c0, uint32_t c1,
                                       uint32_t& o0, uint32_t& o1) {
  uint32_t ks2 = k0 ^ k1 ^ 0x1BD11BDAu;
  uint32_t x0 = c0 + k0, x1 = c1 + k1;
#define TF_R(r) { x0 += x1; x1 = rotl32(x1, (r)); x1 ^= x0; }
  TF_R(13) TF_R(15) TF_R(26) TF_R(6)
  x0 += k1;  x1 += ks2 + 1u;
  TF_R(17) TF_R(29) TF_R(16) TF_R(24)
  x0 += ks2; x1 += k0 + 2u;
  TF_R(13) TF_R(15) TF_R(26) TF_R(6)
  x0 += k0;  x1 += k1 + 3u;
  TF_R(17) TF_R(29) TF_R(16) TF_R(24)
  x0 += k1;  x1 += ks2 + 4u;
  TF_R(13) TF_R(15) TF_R(26) TF_R(6)
  x0 += ks2; x1 += k0 + 5u;
#undef TF_R
  o0 = x0; o1 = x1;
}

// Exact rank value of score = 2.0f + uniform(bits): bits(score) - bits(2.0f).
__device__ __forceinline__ uint32_t pixel_m(uint32_t k0, uint32_t k1, int p) {
  uint32_t b1, b2;
  tf2x32(k0, k1, 0u, (uint32_t)p, b1, b2);
  uint32_t bits = b1 ^ b2;
  float noise = __uint_as_float((bits >> 9) | 0x3F800000u) - 1.0f;
  float score = 2.0f + noise;
  return __float_as_uint(score) - 0x40000000u;  // 0 .. 0x400000 inclusive
}

__device__ __forceinline__ float sigf(float x) { return 1.0f / (1.0f + __expf(-x)); }

__device__ __forceinline__ float ldval(const float* __restrict__ img, int r, int c, bool isPred) {
  if (r < 0 || r > HH - 1 || c < 0 || c > WW - 1) return 0.0f;  // conv zero-pad (post-sigmoid)
  float v = img[(size_t)r * WW + c];
  return isPred ? sigf(v) : v;
}

__device__ __forceinline__ uint32_t pack_pt(uint32_t p) {
  return ((p >> 9) << 16) | (p & 511u);
}

// ---------------- K1 ----------------
// Load one full row across the wave: lane owns cols [8*lane, 8*lane+8); v[0] and
// v[9] are the left/right halo via in-wave shuffles (wave spans the whole row, so
// only lane 0 / lane 63 touch image-edge columns -> cndmask 0).
template <bool PRED>
__device__ __forceinline__ void load_row10(const float* __restrict__ img, int rn,
                                           int lane, float v[10]) {
  if ((unsigned)rn < (unsigned)HH) {  // wave-uniform branch
    const float* rp = img + ((size_t)rn << 9) + (lane << 3);
    float4 x = *(const float4*)rp;
    float4 y = *(const float4*)(rp + 4);
    if (PRED) {
      x.x = sigf(x.x); x.y = sigf(x.y); x.z = sigf(x.z); x.w = sigf(x.w);
      y.x = sigf(y.x); y.y = sigf(y.y); y.z = sigf(y.z); y.w = sigf(y.w);
    }
    v[1] = x.x; v[2] = x.y; v[3] = x.z; v[4] = x.w;
    v[5] = y.x; v[6] = y.y; v[7] = y.z; v[8] = y.w;
    float l = __shfl_up(y.w, 1);
    float r = __shfl_down(x.x, 1);
    v[0] = (lane == 0) ? 0.0f : l;
    v[9] = (lane == 63) ? 0.0f : r;
  } else {
#pragma unroll
    for (int i = 0; i < 10; ++i) v[i] = 0.0f;
  }
}

template <bool PRED>
__device__ __forceinline__ void sobel_body(const float* __restrict__ img, int b,
                                           int slice, int t,
                                           unsigned long long* stage, int* s_cn,
                                           int* s_cv) {
  const int lane = t & 63, w = t >> 6;
  const int rbase = slice * ROWS_PER + 8 * w;  // this wave's first compute row
  uint32_t k0, k1;
  tf2x32(0u, 1u, 0u, (uint32_t)b, k0, k1);

  float A[10], Bv[10], D[10];
  load_row10<PRED>(img, rbase - 1, lane, A);
  load_row10<PRED>(img, rbase, lane, Bv);

  int cnt = 0;
  int prow = (rbase << 9) + (lane << 3);
  for (int rr = 0; rr < 8; ++rr) {  // rolled; all array indices below constant
    load_row10<PRED>(img, rbase + rr + 1, lane, D);
    float da[10], e[10];
#pragma unroll
    for (int k = 0; k < 10; ++k) {
      da[k] = D[k] - A[k];
      e[k] = A[k] + 2.0f * Bv[k] + D[k];
    }
#pragma unroll
    for (int j = 0; j < 8; ++j) {
      float gx = e[j + 2] - e[j];
      float gy = da[j] + 2.0f * da[j + 1] + da[j + 2];
      bool vld = (gx * gx + gy * gy + 1e-8f) > 0.01f;  // sqrt(x)>0.1 <=> x>0.01
      uint32_t m = pixel_m(k0, k1, prow + j);
      cnt += (int)vld;
      if (vld && m >= CUTM) {
        int i = atomicAdd(s_cn, 1);
        if (i < SLICE_CAP) stage[i] = ((unsigned long long)m << 32) | (uint32_t)(prow + j);
      }
    }
#pragma unroll
    for (int k = 0; k < 10; ++k) { A[k] = Bv[k]; Bv[k] = D[k]; }
    prow += WW;
  }
#pragma unroll
  for (int o = 32; o > 0; o >>= 1) cnt += __shfl_down(cnt, o);
  if (lane == 0) atomicAdd(s_cv, cnt);
}

__global__ __launch_bounds__(256, 4) void sobel_cand(
    const float* __restrict__ pred, const float* __restrict__ tgt,
    int2* __restrict__ g_scnt, unsigned long long* __restrict__ g_cand) {
  const int bid = blockIdx.x;
  const int b = bid >> 4, s = bid & 15;
  const int t = threadIdx.x;
  __shared__ unsigned long long stage[SLICE_CAP];
  __shared__ int s_cn, s_cv;
  if (t == 0) { s_cn = 0; s_cv = 0; }
  __syncthreads();
  if (b < 64) sobel_body<true>(pred + (size_t)b * NPIX, b, s, t, stage, &s_cn, &s_cv);
  else        sobel_body<false>(tgt + (size_t)(b - 64) * NPIX, b, s, t, stage, &s_cn, &s_cv);
  __syncthreads();
  const int raw = s_cn;
  const int n = raw < SLICE_CAP ? raw : SLICE_CAP;
  for (int i = t; i < n; i += 256) g_cand[(size_t)bid * SLICE_CAP + i] = stage[i];
  if (t == 0) g_scnt[bid] = make_int2(s_cv, raw);
}

// ---------------- K2 resolve (1 block per image-side) ----------------
__global__ __launch_bounds__(256) void resolve_kernel(
    const float* __restrict__ pred, const float* __restrict__ tgt,
    const int2* __restrict__ g_scnt, unsigned long long* __restrict__ g_cand,
    uint32_t* __restrict__ g_pts, int* __restrict__ g_counts) {
  const int img = blockIdx.x;
  const int t = threadIdx.x;

  __shared__ int segc[16];
  __shared__ int s_info[4];  // cv, cnt_hi_sum, ovf, ncand_rebuilt
  __shared__ int ch[256];
  __shared__ int fh[1024];
  __shared__ int aux[256];
  __shared__ unsigned long long ties[256];
  __shared__ int s_pos, s_nt, s_T1, s_r1, s_T2, s_r2;

  if (t == 0) {
    int cv = 0, hi = 0, ovf = 0;
    for (int s = 0; s < 16; ++s) {
      int2 v = g_scnt[img * 16 + s];
      cv += v.x;
      hi += v.y;
      segc[s] = v.y < SLICE_CAP ? v.y : SLICE_CAP;
      if (v.y > SLICE_CAP) ovf = 1;
    }
    s_info[0] = cv; s_info[1] = hi; s_info[2] = ovf;
    s_pos = 0; s_nt = 0;
  }
  __syncthreads();
  const int cv = s_info[0];
  if (cv == 0) {  // center fallback
    if (t == 0) { g_pts[img * NSEL] = (256u << 16) | 256u; g_counts[img] = 1; }
    return;
  }
  const int need = cv < NSEL ? cv : NSEL;
  bool slow = (s_info[2] != 0) || (s_info[1] < need);

  unsigned long long* C = g_cand + (size_t)img * 16 * SLICE_CAP;
  int ncand;

  if (slow) {
    // ---- exact rebuild (statistically never taken): rescan whole image ----
    const bool isPred = img < 64;
    const float* im = isPred ? pred + (size_t)img * NPIX : tgt + (size_t)(img - 64) * NPIX;
    uint32_t k0, k1;
    tf2x32(0u, 1u, 0u, (uint32_t)img, k0, k1);
    ch[t] = 0;
    __syncthreads();
    for (int p = t; p < NPIX; p += 256) {
      int r = p >> 9, c = p & 511;
      float gx = (ldval(im, r - 1, c + 1, isPred) - ldval(im, r - 1, c - 1, isPred)) +
                 2.0f * (ldval(im, r, c + 1, isPred) - ldval(im, r, c - 1, isPred)) +
                 (ldval(im, r + 1, c + 1, isPred) - ldval(im, r + 1, c - 1, isPred));
      float gy = (ldval(im, r + 1, c - 1, isPred) - ldval(im, r - 1, c - 1, isPred)) +
                 2.0f * (ldval(im, r + 1, c, isPred) - ldval(im, r - 1, c, isPred)) +
                 (ldval(im, r + 1, c + 1, isPred) - ldval(im, r - 1, c + 1, isPred));
      if ((gx * gx + gy * gy + 1e-8f) > 0.01f) {
        uint32_t m = pixel_m(k0, k1, p);
        uint32_t cb = m >> 14; if (cb > 255u) cb = 255u;
        atomicAdd(&ch[cb], 1);
      }
    }
    __syncthreads();
    {
      aux[t] = ch[t];
      __syncthreads();
      for (int o = 1; o < 256; o <<= 1) {
        int v = (t + o < 256) ? aux[t + o] : 0;
        __syncthreads();
        aux[t] += v;
        __syncthreads();
      }
      int nx = (t + 1 < 256) ? aux[t + 1] : 0;
      if (aux[t] >= need && nx < need) s_T1 = t;
      __syncthreads();
    }
    const uint32_t Tc = (uint32_t)s_T1;
    if (t == 0) s_info[3] = 0;
    __syncthreads();
    for (int p = t; p < NPIX; p += 256) {
      int r = p >> 9, c = p & 511;
      float gx = (ldval(im, r - 1, c + 1, isPred) - ldval(im, r - 1, c - 1, isPred)) +
                 2.0f * (ldval(im, r, c + 1, isPred) - ldval(im, r, c - 1, isPred)) +
                 (ldval(im, r + 1, c + 1, isPred) - ldval(im, r + 1, c - 1, isPred));
      float gy = (ldval(im, r + 1, c - 1, isPred) - ldval(im, r - 1, c - 1, isPred)) +
                 2.0f * (ldval(im, r + 1, c, isPred) - ldval(im, r - 1, c, isPred)) +
                 (ldval(im, r + 1, c + 1, isPred) - ldval(im, r - 1, c + 1, isPred));
      if ((gx * gx + gy * gy + 1e-8f) > 0.01f) {
        uint32_t m = pixel_m(k0, k1, p);
        uint32_t cb = m >> 14; if (cb > 255u) cb = 255u;
        if (cb >= Tc) {
          int i = atomicAdd(&s_info[3], 1);
          if (i < 16 * SLICE_CAP) C[i] = ((unsigned long long)m << 32) | (uint32_t)p;
        }
      }
    }
    __syncthreads();
    ncand = s_info[3] < 16 * SLICE_CAP ? s_info[3] : 16 * SLICE_CAP;
    if (t == 0) { segc[0] = ncand; for (int s = 1; s < 16; ++s) segc[s] = 0; }
    __syncthreads();
  }

  // ---- selection over candidate segments ----
  ch[t] = 0;
  for (int i = t; i < 1024; i += 256) fh[i] = 0;
  __syncthreads();
  for (int s = 0; s < 16; ++s) {
    const unsigned long long* seg = C + (size_t)s * SLICE_CAP;
    for (int i = t; i < segc[s]; i += 256) {
      uint32_t m = (uint32_t)(seg[i] >> 32);
      uint32_t cb = m >> 14; if (cb > 255u) cb = 255u;
      atomicAdd(&ch[cb], 1);
    }
  }
  __syncthreads();
  {
    aux[t] = ch[t];
    __syncthreads();
    for (int o = 1; o < 256; o <<= 1) {
      int v = (t + o < 256) ? aux[t + o] : 0;
      __syncthreads();
      aux[t] += v;
      __syncthreads();
    }
    int nx = (t + 1 < 256) ? aux[t + 1] : 0;
    if (aux[t] >= need && nx < need) { s_T1 = t; s_r1 = need - nx; }
    __syncthreads();
  }
  const uint32_t T1 = (uint32_t)s_T1;
  const int r1 = s_r1;
  const uint32_t baseM = T1 << 14;

  for (int s = 0; s < 16; ++s) {
    const unsigned long long* seg = C + (size_t)s * SLICE_CAP;
    for (int i = t; i < segc[s]; i += 256) {
      unsigned long long e = seg[i];
      uint32_t m = (uint32_t)(e >> 32), p = (uint32_t)e;
      uint32_t cb = m >> 14; if (cb > 255u) cb = 255u;
      if (cb > T1) {
        int pos = atomicAdd(&s_pos, 1);
        g_pts[img * NSEL + pos] = pack_pt(p);
      } else if (cb == T1) {
        uint32_t f = (m - baseM) >> 4; if (f > 1023u) f = 1023u;
        atomicAdd(&fh[f], 1);
      }
    }
  }
  __syncthreads();
  {
    int base = 4 * t, sv = 0;
    for (int j = 3; j >= 0; --j) { sv += fh[base + j]; fh[base + j] = sv; }
    aux[t] = sv;
    __syncthreads();
    for (int o = 1; o < 256; o <<= 1) {
      int v = (t + o < 256) ? aux[t + o] : 0;
      __syncthreads();
      aux[t] += v;
      __syncthreads();
    }
    int add = (t < 255) ? aux[t + 1] : 0;
    for (int j = 0; j < 4; ++j) fh[base + j] += add;
    __syncthreads();
    for (int j = 0; j < 4; ++j) {
      int idx = base + j;
      int sfx = fh[idx];
      int nx = (idx < 1023) ? fh[idx + 1] : 0;
      if (sfx >= r1 && nx < r1) { s_T2 = idx; s_r2 = r1 - nx; }
    }
    __syncthreads();
  }
  const int T2 = s_T2, r2 = s_r2;
  for (int s = 0; s < 16; ++s) {
    const unsigned long long* seg = C + (size_t)s * SLICE_CAP;
    for (int i = t; i < segc[s]; i += 256) {
      unsigned long long e = seg[i];
      uint32_t m = (uint32_t)(e >> 32), p = (uint32_t)e;
      uint32_t cb = m >> 14; if (cb > 255u) cb = 255u;
      if (cb == T1) {
        uint32_t f = (m - baseM) >> 4; if (f > 1023u) f = 1023u;
        if ((int)f > T2) {
          int pos = atomicAdd(&s_pos, 1);
          g_pts[img * NSEL + pos] = pack_pt(p);
        } else if ((int)f == T2) {
          int j = atomicAdd(&s_nt, 1);
          if (j < 256) ties[j] = e;
        }
      }
    }
  }
  __syncthreads();
  int nt = s_nt < 256 ? s_nt : 256;
  for (int i = t; i < nt; i += 256) {
    unsigned long long e = ties[i];
    uint32_t mi = (uint32_t)(e >> 32), pi = (uint32_t)e;
    int rank = 0;
    for (int j = 0; j < nt; ++j) {
      unsigned long long e2 = ties[j];
      uint32_t mj = (uint32_t)(e2 >> 32), pj = (uint32_t)e2;
      rank += (mj > mi) || (mj == mi && pj < pi);
    }
    if (rank < r2) {
      int pos = atomicAdd(&s_pos, 1);
      g_pts[img * NSEL + pos] = pack_pt(pi);
    }
  }
  __syncthreads();
  if (t == 0) g_counts[img] = s_pos;  // == need
}

// ---------------- K3 ----------------
__global__ __launch_bounds__(256) void haus_kernel(
    const uint32_t* __restrict__ g_pts, const int* __restrict__ g_counts,
    float* __restrict__ g_hpart) {
  const int bid = blockIdx.x;
  const int img = bid >> 3;
  const int dir = (bid >> 2) & 1;
  const int seg = bid & 3;
  const int t = threadIdx.x;
  const int iOwn = dir ? 64 + img : img;
  const int iOth = dir ? img : 64 + img;
  const int nOwn = g_counts[iOwn];
  const int nOth = g_counts[iOth];
  __shared__ float2 o[NSEL];
  __shared__ float red[256];
  for (int i = t; i < nOth; i += 256) {
    uint32_t v = g_pts[iOth * NSEL + i];
    o[i] = make_float2((float)(v >> 16), (float)(v & 0xFFFFu));
  }
  __syncthreads();
  float best = 0.0f;
  const int lo = seg * 250;
  const int hi = min(nOwn, lo + 250);
  for (int i = lo + t; i < hi; i += 256) {
    uint32_t v = g_pts[iOwn * NSEL + i];
    float pr = (float)(v >> 16), pc = (float)(v & 0xFFFFu);
    float mn = 3.4e38f;
    for (int j = 0; j < nOth; ++j) {
      float dr = pr - o[j].x, dc = pc - o[j].y;
      mn = fminf(mn, dr * dr + dc * dc);
    }
    best = fmaxf(best, mn);
  }
  red[t] = best;
  __syncthreads();
  for (int st = 128; st > 0; st >>= 1) {
    if (t < st) red[t] = fmaxf(red[t], red[t + st]);
    __syncthreads();
  }
  if (t == 0) g_hpart[bid] = red[0];
}

// ---------------- K4 ----------------
__global__ __launch_bounds__(64) void fin_kernel(const float* __restrict__ g_hpart,
                                                 float* __restrict__ out) {
  const int t = threadIdx.x;  // one thread per image
  float mx = 0.0f;
  for (int j = 0; j < 8; ++j) mx = fmaxf(mx, g_hpart[t * 8 + j]);
  float diag = sqrtf((float)(HH * HH + WW * WW));
  float hd = sqrtf(fmaxf(mx, 0.0f)) / diag;
  hd = fminf(fmaxf(hd, 0.0f), 0.1f);
  float s = hd;
  for (int o = 32; o > 0; o >>= 1) s += __shfl_down(s, o);
  if (t == 0) out[0] = s * 0.015625f;
}

// ---------------- workspace layout (bytes) — nothing pre-zeroed ----------
#define WS_SCNT   0u                          // 2048*8 = 16384
#define WS_COUNTS 16384u                      // 512
#define WS_HPART  (WS_COUNTS + 512u)          // 2048
#define WS_PTS    (WS_HPART + 2048u)          // 512000
#define WS_CAND   (WS_PTS + 512000u)          // 2048*320*8 = 5242880  (~5.5 MB total)

extern "C" void kernel_launch(void* const* d_in, const int* in_sizes, int n_in,
                              void* d_out, int out_size, void* d_ws, size_t ws_size,
                              hipStream_t stream) {
  const float* pred = (const float*)d_in[0];
  const float* tgt = (const float*)d_in[1];
  float* out = (float*)d_out;
  char* ws = (char*)d_ws;
  int2* g_scnt = (int2*)(ws + WS_SCNT);
  int* g_counts = (int*)(ws + WS_COUNTS);
  float* g_hpart = (float*)(ws + WS_HPART);
  uint32_t* g_pts = (uint32_t*)(ws + WS_PTS);
  unsigned long long* g_cand = (unsigned long long*)(ws + WS_CAND);

  sobel_cand<<<2048, 256, 0, stream>>>(pred, tgt, g_scnt, g_cand);
  resolve_kernel<<<128, 256, 0, stream>>>(pred, tgt, g_scnt, g_cand, g_pts, g_counts);
  haus_kernel<<<512, 256, 0, stream>>>(g_pts, g_counts, g_hpart);
  fin_kernel<<<1, 64, 0, stream>>>(g_hpart, out);
}

// Round 8
// 284.915 us; speedup vs baseline: 1.1377x; 1.0636x over previous
//
#include <hip/hip_runtime.h>
#include <stdint.h>

// GPUHausdorffLoss — R8: K1 with straight-line 8-chain threefry (explicit ILP),
// raw-bits candidate test (no per-pixel m finalize), mask-driven staging.
//  K1 sobel_cand (2048 blk = 128 img-sides x 16 slices; wave w of 4 owns rows
//     [slice*32+8w, +8), lane owns 8 cols): Sobel valid + threefry bits once/px;
//     stage (m,p) when bits >= BITCUT (== m >= 253<<14); per-slice (cv,raw).
//  K2 resolve (128 blk, 1/img): coarse-256/fine-1024 radix select + exact
//     (m desc, idx asc) ties; exact slow-path rebuild on shortfall/overflow
//     (statistically never); center fallback cv==0.
//  K3 haus (512 blk): per (img,dir,seg) partial max of min d^2 -> g_hpart.
//  K4 fin (1x64): reduce 8 partials/img, clip, mean -> out[0].

#define HH 512
#define WW 512
#define NPIX (HH * WW)
#define NSEL 1000
#define SLICE_CAP 320
#define CUTM (253u << 14)                     // m-threshold (top 3 of 256 bins)
#define BITCUT ((((253u << 15) - 1u)) << 9)   // bits >= BITCUT  <=>  m >= CUTM
#define ROWS_PER 32

#if __has_builtin(__builtin_amdgcn_alignbit)
__device__ __forceinline__ uint32_t rotl32(uint32_t x, int r) {
  return __builtin_amdgcn_alignbit(x, x, (32 - r) & 31);
}
#else
__device__ __forceinline__ uint32_t rotl32(uint32_t x, int r) {
  return (x << r) | (x >> (32 - r));
}
#endif

// JAX threefry2x32: 20 rounds, key schedule every 4.
__device__ __forceinline__ void tf2x32(uint32_t k0, uint32_t k1,
                                       uint32_t c0, uint32_t c1,
                                       uint32_t& o0, uint32_t& o1) {
  uint32_t ks2 = k0 ^ k1 ^ 0x1BD11BDAu;
  uint32_t x0 = c0 + k0, x1 = c1 + k1;
#define TF_R(r) { x0 += x1; x1 = rotl32(x1, (r)); x1 ^= x0; }
  TF_R(13) TF_R(15) TF_R(26) TF_R(6)
  x0 += k1;  x1 += ks2 + 1u;
  TF_R(17) TF_R(29) TF_R(16) TF_R(24)
  x0 += ks2; x1 += k0 + 2u;
  TF_R(13) TF_R(15) TF_R(26) TF_R(6)
  x0 += k0;  x1 += k1 + 3u;
  TF_R(17) TF_R(29) TF_R(16) TF_R(24)
  x0 += k1;  x1 += ks2 + 4u;
  TF_R(13) TF_R(15) TF_R(26) TF_R(6)
  x0 += ks2; x1 += k0 + 5u;
#undef TF_R
  o0 = x0; o1 = x1;
}

// Specialized for c0==0: x0 starts at k0 (saves the first add; key consts uniform).
__device__ __forceinline__ uint32_t tf_bits(uint32_t k0, uint32_t k1, uint32_t p) {
  uint32_t ks2 = k0 ^ k1 ^ 0x1BD11BDAu;
  uint32_t x0 = k0, x1 = p + k1;
#define TF_R(r) { x0 += x1; x1 = rotl32(x1, (r)); x1 ^= x0; }
  TF_R(13) TF_R(15) TF_R(26) TF_R(6)
  x0 += k1;  x1 += ks2 + 1u;
  TF_R(17) TF_R(29) TF_R(16) TF_R(24)
  x0 += ks2; x1 += k0 + 2u;
  TF_R(13) TF_R(15) TF_R(26) TF_R(6)
  x0 += k0;  x1 += k1 + 3u;
  TF_R(17) TF_R(29) TF_R(16) TF_R(24)
  x0 += k1;  x1 += ks2 + 4u;
  TF_R(13) TF_R(15) TF_R(26) TF_R(6)
  x0 += ks2; x1 += k0 + 5u;
#undef TF_R
  return x0 ^ x1;
}

// Exact rank value of score = 2.0f + uniform(bits): bits(score) - bits(2.0f).
__device__ __forceinline__ uint32_t m_from_bits(uint32_t bits) {
  float noise = __uint_as_float((bits >> 9) | 0x3F800000u) - 1.0f;
  float score = 2.0f + noise;
  return __float_as_uint(score) - 0x40000000u;  // 0 .. 0x400000 inclusive
}

__device__ __forceinline__ uint32_t pixel_m(uint32_t k0, uint32_t k1, int p) {
  uint32_t b1, b2;
  tf2x32(k0, k1, 0u, (uint32_t)p, b1, b2);
  return m_from_bits(b1 ^ b2);
}

__device__ __forceinline__ float sigf(float x) { return 1.0f / (1.0f + __expf(-x)); }

__device__ __forceinline__ float ldval(const float* __restrict__ img, int r, int c, bool isPred) {
  if (r < 0 || r > HH - 1 || c < 0 || c > WW - 1) return 0.0f;  // conv zero-pad (post-sigmoid)
  float v = img[(size_t)r * WW + c];
  return isPred ? sigf(v) : v;
}

__device__ __forceinline__ uint32_t pack_pt(uint32_t p) {
  return ((p >> 9) << 16) | (p & 511u);
}

// ---------------- K1 ----------------
// Wave spans a full 512-col row: lane owns cols [8*lane, 8*lane+8); v[0]/v[9]
// are halos via in-wave shuffles (edge lanes get the conv zero-pad).
template <bool PRED>
__device__ __forceinline__ void load_row10(const float* __restrict__ img, int rn,
                                           int lane, float v[10]) {
  if ((unsigned)rn < (unsigned)HH) {  // wave-uniform branch
    const float* rp = img + ((size_t)rn << 9) + (lane << 3);
    float4 x = *(const float4*)rp;
    float4 y = *(const float4*)(rp + 4);
    if (PRED) {
      x.x = sigf(x.x); x.y = sigf(x.y); x.z = sigf(x.z); x.w = sigf(x.w);
      y.x = sigf(y.x); y.y = sigf(y.y); y.z = sigf(y.z); y.w = sigf(y.w);
    }
    v[1] = x.x; v[2] = x.y; v[3] = x.z; v[4] = x.w;
    v[5] = y.x; v[6] = y.y; v[7] = y.z; v[8] = y.w;
    float l = __shfl_up(y.w, 1);
    float r = __shfl_down(x.x, 1);
    v[0] = (lane == 0) ? 0.0f : l;
    v[9] = (lane == 63) ? 0.0f : r;
  } else {
#pragma unroll
    for (int i = 0; i < 10; ++i) v[i] = 0.0f;
  }
}

template <bool PRED>
__device__ __forceinline__ void sobel_body(const float* __restrict__ img, int b,
                                           int slice, int t,
                                           unsigned long long* stage, int* s_cn,
                                           int* s_cv) {
  const int lane = t & 63, w = t >> 6;
  const int rbase = slice * ROWS_PER + 8 * w;  // this wave's first compute row
  uint32_t k0, k1;
  tf2x32(0u, 1u, 0u, (uint32_t)b, k0, k1);

  float A[10], Bv[10], D[10];
  load_row10<PRED>(img, rbase - 1, lane, A);
  load_row10<PRED>(img, rbase, lane, Bv);

  int cnt = 0;
  uint32_t prow = (uint32_t)((rbase << 9) + (lane << 3));
  for (int rr = 0; rr < 8; ++rr) {  // rolled: keeps VGPR < 128
    load_row10<PRED>(img, rbase + rr + 1, lane, D);

    // straight-line block of 8 independent threefry chains (explicit ILP)
    uint32_t bits[8];
#pragma unroll
    for (int j = 0; j < 8; ++j) bits[j] = tf_bits(k0, k1, prow + (uint32_t)j);

    float da[10], e[10];
#pragma unroll
    for (int k = 0; k < 10; ++k) {
      da[k] = D[k] - A[k];
      e[k] = A[k] + 2.0f * Bv[k] + D[k];
    }
    uint32_t vldmask = 0, candmask = 0;
#pragma unroll
    for (int j = 0; j < 8; ++j) {
      float gx = e[j + 2] - e[j];
      float gy = da[j] + 2.0f * da[j + 1] + da[j + 2];
      bool vld = (gx * gx + gy * gy + 1e-8f) > 0.01f;  // sqrt(x)>0.1 <=> x>0.01
      vldmask |= (vld ? 1u : 0u) << j;
      candmask |= ((vld && bits[j] >= BITCUT) ? 1u : 0u) << j;
    }
    cnt += __popc(vldmask);

    while (candmask) {  // rare: ~1.2% of pixels; expected <=2 iters per wave
      int j = __ffs(candmask) - 1;
      candmask &= candmask - 1;
      uint32_t m = m_from_bits(bits[j]);
      int i = atomicAdd(s_cn, 1);
      if (i < SLICE_CAP)
        stage[i] = ((unsigned long long)m << 32) | (prow + (uint32_t)j);
    }

#pragma unroll
    for (int k = 0; k < 10; ++k) { A[k] = Bv[k]; Bv[k] = D[k]; }
    prow += WW;
  }
#pragma unroll
  for (int o = 32; o > 0; o >>= 1) cnt += __shfl_down(cnt, o);
  if (lane == 0) atomicAdd(s_cv, cnt);
}

__global__ __launch_bounds__(256, 4) void sobel_cand(
    const float* __restrict__ pred, const float* __restrict__ tgt,
    int2* __restrict__ g_scnt, unsigned long long* __restrict__ g_cand) {
  const int bid = blockIdx.x;
  const int b = bid >> 4, s = bid & 15;
  const int t = threadIdx.x;
  __shared__ unsigned long long stage[SLICE_CAP];
  __shared__ int s_cn, s_cv;
  if (t == 0) { s_cn = 0; s_cv = 0; }
  __syncthreads();
  if (b < 64) sobel_body<true>(pred + (size_t)b * NPIX, b, s, t, stage, &s_cn, &s_cv);
  else        sobel_body<false>(tgt + (size_t)(b - 64) * NPIX, b, s, t, stage, &s_cn, &s_cv);
  __syncthreads();
  const int raw = s_cn;
  const int n = raw < SLICE_CAP ? raw : SLICE_CAP;
  for (int i = t; i < n; i += 256) g_cand[(size_t)bid * SLICE_CAP + i] = stage[i];
  if (t == 0) g_scnt[bid] = make_int2(s_cv, raw);
}

// ---------------- K2 resolve (1 block per image-side) ----------------
__global__ __launch_bounds__(256) void resolve_kernel(
    const float* __restrict__ pred, const float* __restrict__ tgt,
    const int2* __restrict__ g_scnt, unsigned long long* __restrict__ g_cand,
    uint32_t* __restrict__ g_pts, int* __restrict__ g_counts) {
  const int img = blockIdx.x;
  const int t = threadIdx.x;

  __shared__ int segc[16];
  __shared__ int s_info[4];  // cv, cnt_hi_sum, ovf, ncand_rebuilt
  __shared__ int ch[256];
  __shared__ int fh[1024];
  __shared__ int aux[256];
  __shared__ unsigned long long ties[256];
  __shared__ int s_pos, s_nt, s_T1, s_r1, s_T2, s_r2;

  if (t == 0) {
    int cv = 0, hi = 0, ovf = 0;
    for (int s = 0; s < 16; ++s) {
      int2 v = g_scnt[img * 16 + s];
      cv += v.x;
      hi += v.y;
      segc[s] = v.y < SLICE_CAP ? v.y : SLICE_CAP;
      if (v.y > SLICE_CAP) ovf = 1;
    }
    s_info[0] = cv; s_info[1] = hi; s_info[2] = ovf;
    s_pos = 0; s_nt = 0;
  }
  __syncthreads();
  const int cv = s_info[0];
  if (cv == 0) {  // center fallback
    if (t == 0) { g_pts[img * NSEL] = (256u << 16) | 256u; g_counts[img] = 1; }
    return;
  }
  const int need = cv < NSEL ? cv : NSEL;
  bool slow = (s_info[2] != 0) || (s_info[1] < need);

  unsigned long long* C = g_cand + (size_t)img * 16 * SLICE_CAP;
  int ncand;

  if (slow) {
    // ---- exact rebuild (statistically never taken): rescan whole image ----
    const bool isPred = img < 64;
    const float* im = isPred ? pred + (size_t)img * NPIX : tgt + (size_t)(img - 64) * NPIX;
    uint32_t k0, k1;
    tf2x32(0u, 1u, 0u, (uint32_t)img, k0, k1);
    ch[t] = 0;
    __syncthreads();
    for (int p = t; p < NPIX; p += 256) {
      int r = p >> 9, c = p & 511;
      float gx = (ldval(im, r - 1, c + 1, isPred) - ldval(im, r - 1, c - 1, isPred)) +
                 2.0f * (ldval(im, r, c + 1, isPred) - ldval(im, r, c - 1, isPred)) +
                 (ldval(im, r + 1, c + 1, isPred) - ldval(im, r + 1, c - 1, isPred));
      float gy = (ldval(im, r + 1, c - 1, isPred) - ldval(im, r - 1, c - 1, isPred)) +
                 2.0f * (ldval(im, r + 1, c, isPred) - ldval(im, r - 1, c, isPred)) +
                 (ldval(im, r + 1, c + 1, isPred) - ldval(im, r - 1, c + 1, isPred));
      if ((gx * gx + gy * gy + 1e-8f) > 0.01f) {
        uint32_t m = pixel_m(k0, k1, p);
        uint32_t cb = m >> 14; if (cb > 255u) cb = 255u;
        atomicAdd(&ch[cb], 1);
      }
    }
    __syncthreads();
    {
      aux[t] = ch[t];
      __syncthreads();
      for (int o = 1; o < 256; o <<= 1) {
        int v = (t + o < 256) ? aux[t + o] : 0;
        __syncthreads();
        aux[t] += v;
        __syncthreads();
      }
      int nx = (t + 1 < 256) ? aux[t + 1] : 0;
      if (aux[t] >= need && nx < need) s_T1 = t;
      __syncthreads();
    }
    const uint32_t Tc = (uint32_t)s_T1;
    if (t == 0) s_info[3] = 0;
    __syncthreads();
    for (int p = t; p < NPIX; p += 256) {
      int r = p >> 9, c = p & 511;
      float gx = (ldval(im, r - 1, c + 1, isPred) - ldval(im, r - 1, c - 1, isPred)) +
                 2.0f * (ldval(im, r, c + 1, isPred) - ldval(im, r, c - 1, isPred)) +
                 (ldval(im, r + 1, c + 1, isPred) - ldval(im, r + 1, c - 1, isPred));
      float gy = (ldval(im, r + 1, c - 1, isPred) - ldval(im, r - 1, c - 1, isPred)) +
                 2.0f * (ldval(im, r + 1, c, isPred) - ldval(im, r - 1, c, isPred)) +
                 (ldval(im, r + 1, c + 1, isPred) - ldval(im, r - 1, c + 1, isPred));
      if ((gx * gx + gy * gy + 1e-8f) > 0.01f) {
        uint32_t m = pixel_m(k0, k1, p);
        uint32_t cb = m >> 14; if (cb > 255u) cb = 255u;
        if (cb >= Tc) {
          int i = atomicAdd(&s_info[3], 1);
          if (i < 16 * SLICE_CAP) C[i] = ((unsigned long long)m << 32) | (uint32_t)p;
        }
      }
    }
    __syncthreads();
    ncand = s_info[3] < 16 * SLICE_CAP ? s_info[3] : 16 * SLICE_CAP;
    if (t == 0) { segc[0] = ncand; for (int s = 1; s < 16; ++s) segc[s] = 0; }
    __syncthreads();
  }

  // ---- selection over candidate segments ----
  ch[t] = 0;
  for (int i = t; i < 1024; i += 256) fh[i] = 0;
  __syncthreads();
  for (int s = 0; s < 16; ++s) {
    const unsigned long long* seg = C + (size_t)s * SLICE_CAP;
    for (int i = t; i < segc[s]; i += 256) {
      uint32_t m = (uint32_t)(seg[i] >> 32);
      uint32_t cb = m >> 14; if (cb > 255u) cb = 255u;
      atomicAdd(&ch[cb], 1);
    }
  }
  __syncthreads();
  {
    aux[t] = ch[t];
    __syncthreads();
    for (int o = 1; o < 256; o <<= 1) {
      int v = (t + o < 256) ? aux[t + o] : 0;
      __syncthreads();
      aux[t] += v;
      __syncthreads();
    }
    int nx = (t + 1 < 256) ? aux[t + 1] : 0;
    if (aux[t] >= need && nx < need) { s_T1 = t; s_r1 = need - nx; }
    __syncthreads();
  }
  const uint32_t T1 = (uint32_t)s_T1;
  const int r1 = s_r1;
  const uint32_t baseM = T1 << 14;

  for (int s = 0; s < 16; ++s) {
    const unsigned long long* seg = C + (size_t)s * SLICE_CAP;
    for (int i = t; i < segc[s]; i += 256) {
      unsigned long long e = seg[i];
      uint32_t m = (uint32_t)(e >> 32), p = (uint32_t)e;
      uint32_t cb = m >> 14; if (cb > 255u) cb = 255u;
      if (cb > T1) {
        int pos = atomicAdd(&s_pos, 1);
        g_pts[img * NSEL + pos] = pack_pt(p);
      } else if (cb == T1) {
        uint32_t f = (m - baseM) >> 4; if (f > 1023u) f = 1023u;
        atomicAdd(&fh[f], 1);
      }
    }
  }
  __syncthreads();
  {
    int base = 4 * t, sv = 0;
    for (int j = 3; j >= 0; --j) { sv += fh[base + j]; fh[base + j] = sv; }
    aux[t] = sv;
    __syncthreads();
    for (int o = 1; o < 256; o <<= 1) {
      int v = (t + o < 256) ? aux[t + o] : 0;
      __syncthreads();
      aux[t] += v;
      __syncthreads();
    }
    int add = (t < 255) ? aux[t + 1] : 0;
    for (int j = 0; j < 4; ++j) fh[base + j] += add;
    __syncthreads();
    for (int j = 0; j < 4; ++j) {
      int idx = base + j;
      int sfx = fh[idx];
      int nx = (idx < 1023) ? fh[idx + 1] : 0;
      if (sfx >= r1 && nx < r1) { s_T2 = idx; s_r2 = r1 - nx; }
    }
    __syncthreads();
  }
  const int T2 = s_T2, r2 = s_r2;
  for (int s = 0; s < 16; ++s) {
    const unsigned long long* seg = C + (size_t)s * SLICE_CAP;
    for (int i = t; i < segc[s]; i += 256) {
      unsigned long long e = seg[i];
      uint32_t m = (uint32_t)(e >> 32), p = (uint32_t)e;
      uint32_t cb = m >> 14; if (cb > 255u) cb = 255u;
      if (cb == T1) {
        uint32_t f = (m - baseM) >> 4; if (f > 1023u) f = 1023u;
        if ((int)f > T2) {
          int pos = atomicAdd(&s_pos, 1);
          g_pts[img * NSEL + pos] = pack_pt(p);
        } else if ((int)f == T2) {
          int j = atomicAdd(&s_nt, 1);
          if (j < 256) ties[j] = e;
        }
      }
    }
  }
  __syncthreads();
  int nt = s_nt < 256 ? s_nt : 256;
  for (int i = t; i < nt; i += 256) {
    unsigned long long e = ties[i];
    uint32_t mi = (uint32_t)(e >> 32), pi = (uint32_t)e;
    int rank = 0;
    for (int j = 0; j < nt; ++j) {
      unsigned long long e2 = ties[j];
      uint32_t mj = (uint32_t)(e2 >> 32), pj = (uint32_t)e2;
      rank += (mj > mi) || (mj == mi && pj < pi);
    }
    if (rank < r2) {
      int pos = atomicAdd(&s_pos, 1);
      g_pts[img * NSEL + pos] = pack_pt(pi);
    }
  }
  __syncthreads();
  if (t == 0) g_counts[img] = s_pos;  // == need
}

// ---------------- K3 ----------------
__global__ __launch_bounds__(256) void haus_kernel(
    const uint32_t* __restrict__ g_pts, const int* __restrict__ g_counts,
    float* __restrict__ g_hpart) {
  const int bid = blockIdx.x;
  const int img = bid >> 3;
  const int dir = (bid >> 2) & 1;
  const int seg = bid & 3;
  const int t = threadIdx.x;
  const int iOwn = dir ? 64 + img : img;
  const int iOth = dir ? img : 64 + img;
  const int nOwn = g_counts[iOwn];
  const int nOth = g_counts[iOth];
  __shared__ float2 o[NSEL];
  __shared__ float red[256];
  for (int i = t; i < nOth; i += 256) {
    uint32_t v = g_pts[iOth * NSEL + i];
    o[i] = make_float2((float)(v >> 16), (float)(v & 0xFFFFu));
  }
  __syncthreads();
  float best = 0.0f;
  const int lo = seg * 250;
  const int hi = min(nOwn, lo + 250);
  for (int i = lo + t; i < hi; i += 256) {
    uint32_t v = g_pts[iOwn * NSEL + i];
    float pr = (float)(v >> 16), pc = (float)(v & 0xFFFFu);
    float mn = 3.4e38f;
    for (int j = 0; j < nOth; ++j) {
      float dr = pr - o[j].x, dc = pc - o[j].y;
      mn = fminf(mn, dr * dr + dc * dc);
    }
    best = fmaxf(best, mn);
  }
  red[t] = best;
  __syncthreads();
  for (int st = 128; st > 0; st >>= 1) {
    if (t < st) red[t] = fmaxf(red[t], red[t + st]);
    __syncthreads();
  }
  if (t == 0) g_hpart[bid] = red[0];
}

// ---------------- K4 ----------------
__global__ __launch_bounds__(64) void fin_kernel(const float* __restrict__ g_hpart,
                                                 float* __restrict__ out) {
  const int t = threadIdx.x;  // one thread per image
  float mx = 0.0f;
  for (int j = 0; j < 8; ++j) mx = fmaxf(mx, g_hpart[t * 8 + j]);
  float diag = sqrtf((float)(HH * HH + WW * WW));
  float hd = sqrtf(fmaxf(mx, 0.0f)) / diag;
  hd = fminf(fmaxf(hd, 0.0f), 0.1f);
  float s = hd;
  for (int o = 32; o > 0; o >>= 1) s += __shfl_down(s, o);
  if (t == 0) out[0] = s * 0.015625f;
}

// ---------------- workspace layout (bytes) — nothing pre-zeroed ----------
#define WS_SCNT   0u                          // 2048*8 = 16384
#define WS_COUNTS 16384u                      // 512
#define WS_HPART  (WS_COUNTS + 512u)          // 2048
#define WS_PTS    (WS_HPART + 2048u)          // 512000
#define WS_CAND   (WS_PTS + 512000u)          // 2048*320*8 = 5242880  (~5.5 MB total)

extern "C" void kernel_launch(void* const* d_in, const int* in_sizes, int n_in,
                              void* d_out, int out_size, void* d_ws, size_t ws_size,
                              hipStream_t stream) {
  const float* pred = (const float*)d_in[0];
  const float* tgt = (const float*)d_in[1];
  float* out = (float*)d_out;
  char* ws = (char*)d_ws;
  int2* g_scnt = (int2*)(ws + WS_SCNT);
  int* g_counts = (int*)(ws + WS_COUNTS);
  float* g_hpart = (float*)(ws + WS_HPART);
  uint32_t* g_pts = (uint32_t*)(ws + WS_PTS);
  unsigned long long* g_cand = (unsigned long long*)(ws + WS_CAND);

  sobel_cand<<<2048, 256, 0, stream>>>(pred, tgt, g_scnt, g_cand);
  resolve_kernel<<<128, 256, 0, stream>>>(pred, tgt, g_scnt, g_cand, g_pts, g_counts);
  haus_kernel<<<512, 256, 0, stream>>>(g_pts, g_counts, g_hpart);
  fin_kernel<<<1, 64, 0, stream>>>(g_hpart, out);
}

// Round 9
// 243.789 us; speedup vs baseline: 1.3296x; 1.1687x over previous
//
#include <hip/hip_runtime.h>
#include <stdint.h>

// GPUHausdorffLoss — R9: K1 unroll-4 row groups (batched loads, 6-buffer
// rotation = 5 movs/row), R8's bits-compare + rare while-staging per row;
// haus with 4 independent min-accumulators (break fmin chain latency).
//  K1 sobel_cand (2048 blk = 128 img-sides x 16 slices; wave w of 4 owns rows
//     [slice*32+8w, +8), lane owns 8 cols).
//  K2 resolve (128 blk, 1/img): coarse-256/fine-1024 radix select + exact
//     (m desc, idx asc) ties; exact slow-path rebuild (statistically never).
//  K3 haus (512 blk): per (img,dir,seg) partial max of min d^2 -> g_hpart.
//  K4 fin (1x64): reduce 8 partials/img, clip, mean -> out[0].

#define HH 512
#define WW 512
#define NPIX (HH * WW)
#define NSEL 1000
#define SLICE_CAP 320
#define CUTM (253u << 14)                     // m-threshold (top 3 of 256 bins)
#define BITCUT ((((253u << 15) - 1u)) << 9)   // bits >= BITCUT  <=>  m >= CUTM
#define ROWS_PER 32

#if __has_builtin(__builtin_amdgcn_alignbit)
__device__ __forceinline__ uint32_t rotl32(uint32_t x, int r) {
  return __builtin_amdgcn_alignbit(x, x, (32 - r) & 31);
}
#else
__device__ __forceinline__ uint32_t rotl32(uint32_t x, int r) {
  return (x << r) | (x >> (32 - r));
}
#endif

// JAX threefry2x32: 20 rounds, key schedule every 4.
__device__ __forceinline__ void tf2x32(uint32_t k0, uint32_t k1,
                                       uint32_t c0, uint32_t c1,
                                       uint32_t& o0, uint32_t& o1) {
  uint32_t ks2 = k0 ^ k1 ^ 0x1BD11BDAu;
  uint32_t x0 = c0 + k0, x1 = c1 + k1;
#define TF_R(r) { x0 += x1; x1 = rotl32(x1, (r)); x1 ^= x0; }
  TF_R(13) TF_R(15) TF_R(26) TF_R(6)
  x0 += k1;  x1 += ks2 + 1u;
  TF_R(17) TF_R(29) TF_R(16) TF_R(24)
  x0 += ks2; x1 += k0 + 2u;
  TF_R(13) TF_R(15) TF_R(26) TF_R(6)
  x0 += k0;  x1 += k1 + 3u;
  TF_R(17) TF_R(29) TF_R(16) TF_R(24)
  x0 += k1;  x1 += ks2 + 4u;
  TF_R(13) TF_R(15) TF_R(26) TF_R(6)
  x0 += ks2; x1 += k0 + 5u;
#undef TF_R
  o0 = x0; o1 = x1;
}

// Specialized for c0==0 (key-derived constants are wave-uniform SGPRs).
__device__ __forceinline__ uint32_t tf_bits(uint32_t k0, uint32_t k1, uint32_t p) {
  uint32_t ks2 = k0 ^ k1 ^ 0x1BD11BDAu;
  uint32_t x0 = k0, x1 = p + k1;
#define TF_R(r) { x0 += x1; x1 = rotl32(x1, (r)); x1 ^= x0; }
  TF_R(13) TF_R(15) TF_R(26) TF_R(6)
  x0 += k1;  x1 += ks2 + 1u;
  TF_R(17) TF_R(29) TF_R(16) TF_R(24)
  x0 += ks2; x1 += k0 + 2u;
  TF_R(13) TF_R(15) TF_R(26) TF_R(6)
  x0 += k0;  x1 += k1 + 3u;
  TF_R(17) TF_R(29) TF_R(16) TF_R(24)
  x0 += k1;  x1 += ks2 + 4u;
  TF_R(13) TF_R(15) TF_R(26) TF_R(6)
  x0 += ks2; x1 += k0 + 5u;
#undef TF_R
  return x0 ^ x1;
}

// Exact rank value of score = 2.0f + uniform(bits): bits(score) - bits(2.0f).
__device__ __forceinline__ uint32_t m_from_bits(uint32_t bits) {
  float noise = __uint_as_float((bits >> 9) | 0x3F800000u) - 1.0f;
  float score = 2.0f + noise;
  return __float_as_uint(score) - 0x40000000u;  // 0 .. 0x400000 inclusive
}

__device__ __forceinline__ uint32_t pixel_m(uint32_t k0, uint32_t k1, int p) {
  uint32_t b1, b2;
  tf2x32(k0, k1, 0u, (uint32_t)p, b1, b2);
  return m_from_bits(b1 ^ b2);
}

__device__ __forceinline__ float sigf(float x) { return 1.0f / (1.0f + __expf(-x)); }

__device__ __forceinline__ float ldval(const float* __restrict__ img, int r, int c, bool isPred) {
  if (r < 0 || r > HH - 1 || c < 0 || c > WW - 1) return 0.0f;  // conv zero-pad (post-sigmoid)
  float v = img[(size_t)r * WW + c];
  return isPred ? sigf(v) : v;
}

__device__ __forceinline__ uint32_t pack_pt(uint32_t p) {
  return ((p >> 9) << 16) | (p & 511u);
}

// ---------------- K1 ----------------
// Wave spans a full 512-col row: lane owns cols [8*lane, 8*lane+8); v[0]/v[9]
// are halos via in-wave shuffles (edge lanes get the conv zero-pad).
template <bool PRED>
__device__ __forceinline__ void load_row10(const float* __restrict__ img, int rn,
                                           int lane, float v[10]) {
  if ((unsigned)rn < (unsigned)HH) {  // wave-uniform branch
    const float* rp = img + ((size_t)rn << 9) + (lane << 3);
    float4 x = *(const float4*)rp;
    float4 y = *(const float4*)(rp + 4);
    if (PRED) {
      x.x = sigf(x.x); x.y = sigf(x.y); x.z = sigf(x.z); x.w = sigf(x.w);
      y.x = sigf(y.x); y.y = sigf(y.y); y.z = sigf(y.z); y.w = sigf(y.w);
    }
    v[1] = x.x; v[2] = x.y; v[3] = x.z; v[4] = x.w;
    v[5] = y.x; v[6] = y.y; v[7] = y.z; v[8] = y.w;
    float l = __shfl_up(y.w, 1);
    float r = __shfl_down(x.x, 1);
    v[0] = (lane == 0) ? 0.0f : l;
    v[9] = (lane == 63) ? 0.0f : r;
  } else {
#pragma unroll
    for (int i = 0; i < 10; ++i) v[i] = 0.0f;
  }
}

template <bool PRED>
__device__ __forceinline__ void sobel_body(const float* __restrict__ img, int b,
                                           int slice, int t,
                                           unsigned long long* stage, int* s_cn,
                                           int* s_cv) {
  const int lane = t & 63, w = t >> 6;
  const int rbase = slice * ROWS_PER + 8 * w;  // this wave's first compute row
  uint32_t k0, k1;
  tf2x32(0u, 1u, 0u, (uint32_t)b, k0, k1);

  float A[10], B_[10], C_[10], D_[10], E_[10], F_[10];
  load_row10<PRED>(img, rbase - 1, lane, A);
  load_row10<PRED>(img, rbase, lane, B_);

  int cnt = 0;
  uint32_t prow = (uint32_t)((rbase << 9) + (lane << 3));

  // per-row: threefry bits[8] straight-line, sobel from (P=r-1,Q=r,R=r+1),
  // mask-collect, rare while-staging.
  auto do_row = [&](const float (&P)[10], const float (&Q)[10], const float (&R)[10],
                    uint32_t prow_r) {
    uint32_t bits[8];
#pragma unroll
    for (int j = 0; j < 8; ++j) bits[j] = tf_bits(k0, k1, prow_r + (uint32_t)j);
    float da[10], e[10];
#pragma unroll
    for (int k = 0; k < 10; ++k) {
      da[k] = R[k] - P[k];
      e[k] = P[k] + 2.0f * Q[k] + R[k];
    }
    uint32_t vldmask = 0, candmask = 0;
#pragma unroll
    for (int j = 0; j < 8; ++j) {
      float gx = e[j + 2] - e[j];
      float gy = da[j] + 2.0f * da[j + 1] + da[j + 2];
      bool vld = (gx * gx + gy * gy + 1e-8f) > 0.01f;  // sqrt(x)>0.1 <=> x>0.01
      vldmask |= (vld ? 1u : 0u) << j;
      candmask |= ((vld && bits[j] >= BITCUT) ? 1u : 0u) << j;
    }
    cnt += __popc(vldmask);
    while (candmask) {  // rare: ~1.2% of pixels
      int j = __ffs(candmask) - 1;
      candmask &= candmask - 1;
      uint32_t m = m_from_bits(bits[j]);
      int i = atomicAdd(s_cn, 1);
      if (i < SLICE_CAP)
        stage[i] = ((unsigned long long)m << 32) | (prow_r + (uint32_t)j);
    }
  };

#pragma unroll
  for (int g = 0; g < 2; ++g) {  // two groups of 4 rows
    const int r = rbase + 4 * g;
    // batch the 4 row loads (8 float4 in flight)
    load_row10<PRED>(img, r + 1, lane, C_);
    load_row10<PRED>(img, r + 2, lane, D_);
    load_row10<PRED>(img, r + 3, lane, E_);
    load_row10<PRED>(img, r + 4, lane, F_);
    do_row(A, B_, C_, prow);
    do_row(B_, C_, D_, prow + 512);
    do_row(C_, D_, E_, prow + 1024);
    do_row(D_, E_, F_, prow + 1536);
    if (g == 0) {
#pragma unroll
      for (int k = 0; k < 10; ++k) { A[k] = E_[k]; B_[k] = F_[k]; }
      prow += 2048;
    }
  }
#pragma unroll
  for (int o = 32; o > 0; o >>= 1) cnt += __shfl_down(cnt, o);
  if (lane == 0) atomicAdd(s_cv, cnt);
}

__global__ __launch_bounds__(256, 4) void sobel_cand(
    const float* __restrict__ pred, const float* __restrict__ tgt,
    int2* __restrict__ g_scnt, unsigned long long* __restrict__ g_cand) {
  const int bid = blockIdx.x;
  const int b = bid >> 4, s = bid & 15;
  const int t = threadIdx.x;
  __shared__ unsigned long long stage[SLICE_CAP];
  __shared__ int s_cn, s_cv;
  if (t == 0) { s_cn = 0; s_cv = 0; }
  __syncthreads();
  if (b < 64) sobel_body<true>(pred + (size_t)b * NPIX, b, s, t, stage, &s_cn, &s_cv);
  else        sobel_body<false>(tgt + (size_t)(b - 64) * NPIX, b, s, t, stage, &s_cn, &s_cv);
  __syncthreads();
  const int raw = s_cn;
  const int n = raw < SLICE_CAP ? raw : SLICE_CAP;
  for (int i = t; i < n; i += 256) g_cand[(size_t)bid * SLICE_CAP + i] = stage[i];
  if (t == 0) g_scnt[bid] = make_int2(s_cv, raw);
}

// ---------------- K2 resolve (1 block per image-side) ----------------
__global__ __launch_bounds__(256) void resolve_kernel(
    const float* __restrict__ pred, const float* __restrict__ tgt,
    const int2* __restrict__ g_scnt, unsigned long long* __restrict__ g_cand,
    uint32_t* __restrict__ g_pts, int* __restrict__ g_counts) {
  const int img = blockIdx.x;
  const int t = threadIdx.x;

  __shared__ int segc[16];
  __shared__ int s_info[4];  // cv, cnt_hi_sum, ovf, ncand_rebuilt
  __shared__ int ch[256];
  __shared__ int fh[1024];
  __shared__ int aux[256];
  __shared__ unsigned long long ties[256];
  __shared__ int s_pos, s_nt, s_T1, s_r1, s_T2, s_r2;

  if (t == 0) {
    int cv = 0, hi = 0, ovf = 0;
    for (int s = 0; s < 16; ++s) {
      int2 v = g_scnt[img * 16 + s];
      cv += v.x;
      hi += v.y;
      segc[s] = v.y < SLICE_CAP ? v.y : SLICE_CAP;
      if (v.y > SLICE_CAP) ovf = 1;
    }
    s_info[0] = cv; s_info[1] = hi; s_info[2] = ovf;
    s_pos = 0; s_nt = 0;
  }
  __syncthreads();
  const int cv = s_info[0];
  if (cv == 0) {  // center fallback
    if (t == 0) { g_pts[img * NSEL] = (256u << 16) | 256u; g_counts[img] = 1; }
    return;
  }
  const int need = cv < NSEL ? cv : NSEL;
  bool slow = (s_info[2] != 0) || (s_info[1] < need);

  unsigned long long* C = g_cand + (size_t)img * 16 * SLICE_CAP;
  int ncand;

  if (slow) {
    // ---- exact rebuild (statistically never taken): rescan whole image ----
    const bool isPred = img < 64;
    const float* im = isPred ? pred + (size_t)img * NPIX : tgt + (size_t)(img - 64) * NPIX;
    uint32_t k0, k1;
    tf2x32(0u, 1u, 0u, (uint32_t)img, k0, k1);
    ch[t] = 0;
    __syncthreads();
    for (int p = t; p < NPIX; p += 256) {
      int r = p >> 9, c = p & 511;
      float gx = (ldval(im, r - 1, c + 1, isPred) - ldval(im, r - 1, c - 1, isPred)) +
                 2.0f * (ldval(im, r, c + 1, isPred) - ldval(im, r, c - 1, isPred)) +
                 (ldval(im, r + 1, c + 1, isPred) - ldval(im, r + 1, c - 1, isPred));
      float gy = (ldval(im, r + 1, c - 1, isPred) - ldval(im, r - 1, c - 1, isPred)) +
                 2.0f * (ldval(im, r + 1, c, isPred) - ldval(im, r - 1, c, isPred)) +
                 (ldval(im, r + 1, c + 1, isPred) - ldval(im, r - 1, c + 1, isPred));
      if ((gx * gx + gy * gy + 1e-8f) > 0.01f) {
        uint32_t m = pixel_m(k0, k1, p);
        uint32_t cb = m >> 14; if (cb > 255u) cb = 255u;
        atomicAdd(&ch[cb], 1);
      }
    }
    __syncthreads();
    {
      aux[t] = ch[t];
      __syncthreads();
      for (int o = 1; o < 256; o <<= 1) {
        int v = (t + o < 256) ? aux[t + o] : 0;
        __syncthreads();
        aux[t] += v;
        __syncthreads();
      }
      int nx = (t + 1 < 256) ? aux[t + 1] : 0;
      if (aux[t] >= need && nx < need) s_T1 = t;
      __syncthreads();
    }
    const uint32_t Tc = (uint32_t)s_T1;
    if (t == 0) s_info[3] = 0;
    __syncthreads();
    for (int p = t; p < NPIX; p += 256) {
      int r = p >> 9, c = p & 511;
      float gx = (ldval(im, r - 1, c + 1, isPred) - ldval(im, r - 1, c - 1, isPred)) +
                 2.0f * (ldval(im, r, c + 1, isPred) - ldval(im, r, c - 1, isPred)) +
                 (ldval(im, r + 1, c + 1, isPred) - ldval(im, r + 1, c - 1, isPred));
      float gy = (ldval(im, r + 1, c - 1, isPred) - ldval(im, r - 1, c - 1, isPred)) +
                 2.0f * (ldval(im, r + 1, c, isPred) - ldval(im, r - 1, c, isPred)) +
                 (ldval(im, r + 1, c + 1, isPred) - ldval(im, r - 1, c + 1, isPred));
      if ((gx * gx + gy * gy + 1e-8f) > 0.01f) {
        uint32_t m = pixel_m(k0, k1, p);
        uint32_t cb = m >> 14; if (cb > 255u) cb = 255u;
        if (cb >= Tc) {
          int i = atomicAdd(&s_info[3], 1);
          if (i < 16 * SLICE_CAP) C[i] = ((unsigned long long)m << 32) | (uint32_t)p;
        }
      }
    }
    __syncthreads();
    ncand = s_info[3] < 16 * SLICE_CAP ? s_info[3] : 16 * SLICE_CAP;
    if (t == 0) { segc[0] = ncand; for (int s = 1; s < 16; ++s) segc[s] = 0; }
    __syncthreads();
  }

  // ---- selection over candidate segments ----
  ch[t] = 0;
  for (int i = t; i < 1024; i += 256) fh[i] = 0;
  __syncthreads();
  for (int s = 0; s < 16; ++s) {
    const unsigned long long* seg = C + (size_t)s * SLICE_CAP;
    for (int i = t; i < segc[s]; i += 256) {
      uint32_t m = (uint32_t)(seg[i] >> 32);
      uint32_t cb = m >> 14; if (cb > 255u) cb = 255u;
      atomicAdd(&ch[cb], 1);
    }
  }
  __syncthreads();
  {
    aux[t] = ch[t];
    __syncthreads();
    for (int o = 1; o < 256; o <<= 1) {
      int v = (t + o < 256) ? aux[t + o] : 0;
      __syncthreads();
      aux[t] += v;
      __syncthreads();
    }
    int nx = (t + 1 < 256) ? aux[t + 1] : 0;
    if (aux[t] >= need && nx < need) { s_T1 = t; s_r1 = need - nx; }
    __syncthreads();
  }
  const uint32_t T1 = (uint32_t)s_T1;
  const int r1 = s_r1;
  const uint32_t baseM = T1 << 14;

  for (int s = 0; s < 16; ++s) {
    const unsigned long long* seg = C + (size_t)s * SLICE_CAP;
    for (int i = t; i < segc[s]; i += 256) {
      unsigned long long e = seg[i];
      uint32_t m = (uint32_t)(e >> 32), p = (uint32_t)e;
      uint32_t cb = m >> 14; if (cb > 255u) cb = 255u;
      if (cb > T1) {
        int pos = atomicAdd(&s_pos, 1);
        g_pts[img * NSEL + pos] = pack_pt(p);
      } else if (cb == T1) {
        uint32_t f = (m - baseM) >> 4; if (f > 1023u) f = 1023u;
        atomicAdd(&fh[f], 1);
      }
    }
  }
  __syncthreads();
  {
    int base = 4 * t, sv = 0;
    for (int j = 3; j >= 0; --j) { sv += fh[base + j]; fh[base + j] = sv; }
    aux[t] = sv;
    __syncthreads();
    for (int o = 1; o < 256; o <<= 1) {
      int v = (t + o < 256) ? aux[t + o] : 0;
      __syncthreads();
      aux[t] += v;
      __syncthreads();
    }
    int add = (t < 255) ? aux[t + 1] : 0;
    for (int j = 0; j < 4; ++j) fh[base + j] += add;
    __syncthreads();
    for (int j = 0; j < 4; ++j) {
      int idx = base + j;
      int sfx = fh[idx];
      int nx = (idx < 1023) ? fh[idx + 1] : 0;
      if (sfx >= r1 && nx < r1) { s_T2 = idx; s_r2 = r1 - nx; }
    }
    __syncthreads();
  }
  const int T2 = s_T2, r2 = s_r2;
  for (int s = 0; s < 16; ++s) {
    const unsigned long long* seg = C + (size_t)s * SLICE_CAP;
    for (int i = t; i < segc[s]; i += 256) {
      unsigned long long e = seg[i];
      uint32_t m = (uint32_t)(e >> 32), p = (uint32_t)e;
      uint32_t cb = m >> 14; if (cb > 255u) cb = 255u;
      if (cb == T1) {
        uint32_t f = (m - baseM) >> 4; if (f > 1023u) f = 1023u;
        if ((int)f > T2) {
          int pos = atomicAdd(&s_pos, 1);
          g_pts[img * NSEL + pos] = pack_pt(p);
        } else if ((int)f == T2) {
          int j = atomicAdd(&s_nt, 1);
          if (j < 256) ties[j] = e;
        }
      }
    }
  }
  __syncthreads();
  int nt = s_nt < 256 ? s_nt : 256;
  for (int i = t; i < nt; i += 256) {
    unsigned long long e = ties[i];
    uint32_t mi = (uint32_t)(e >> 32), pi = (uint32_t)e;
    int rank = 0;
    for (int j = 0; j < nt; ++j) {
      unsigned long long e2 = ties[j];
      uint32_t mj = (uint32_t)(e2 >> 32), pj = (uint32_t)e2;
      rank += (mj > mi) || (mj == mi && pj < pi);
    }
    if (rank < r2) {
      int pos = atomicAdd(&s_pos, 1);
      g_pts[img * NSEL + pos] = pack_pt(pi);
    }
  }
  __syncthreads();
  if (t == 0) g_counts[img] = s_pos;  // == need
}

// ---------------- K3 ----------------
__global__ __launch_bounds__(256) void haus_kernel(
    const uint32_t* __restrict__ g_pts, const int* __restrict__ g_counts,
    float* __restrict__ g_hpart) {
  const int bid = blockIdx.x;
  const int img = bid >> 3;
  const int dir = (bid >> 2) & 1;
  const int seg = bid & 3;
  const int t = threadIdx.x;
  const int iOwn = dir ? 64 + img : img;
  const int iOth = dir ? img : 64 + img;
  const int nOwn = g_counts[iOwn];
  const int nOth = g_counts[iOth];
  __shared__ float2 o[NSEL];
  __shared__ float red[256];
  for (int i = t; i < nOth; i += 256) {
    uint32_t v = g_pts[iOth * NSEL + i];
    o[i] = make_float2((float)(v >> 16), (float)(v & 0xFFFFu));
  }
  __syncthreads();
  float best = 0.0f;
  const int lo = seg * 250;
  const int hi = min(nOwn, lo + 250);
  for (int i = lo + t; i < hi; i += 256) {
    uint32_t v = g_pts[iOwn * NSEL + i];
    float pr = (float)(v >> 16), pc = (float)(v & 0xFFFFu);
    // 4 independent accumulators: break the serial fmin dependency chain
    float mn0 = 3.4e38f, mn1 = 3.4e38f, mn2 = 3.4e38f, mn3 = 3.4e38f;
    int j = 0;
    for (; j + 3 < nOth; j += 4) {
      float dr0 = pr - o[j].x,     dc0 = pc - o[j].y;
      float dr1 = pr - o[j + 1].x, dc1 = pc - o[j + 1].y;
      float dr2 = pr - o[j + 2].x, dc2 = pc - o[j + 2].y;
      float dr3 = pr - o[j + 3].x, dc3 = pc - o[j + 3].y;
      mn0 = fminf(mn0, dr0 * dr0 + dc0 * dc0);
      mn1 = fminf(mn1, dr1 * dr1 + dc1 * dc1);
      mn2 = fminf(mn2, dr2 * dr2 + dc2 * dc2);
      mn3 = fminf(mn3, dr3 * dr3 + dc3 * dc3);
    }
    for (; j < nOth; ++j) {
      float dr = pr - o[j].x, dc = pc - o[j].y;
      mn0 = fminf(mn0, dr * dr + dc * dc);
    }
    float mn = fminf(fminf(mn0, mn1), fminf(mn2, mn3));
    best = fmaxf(best, mn);
  }
  red[t] = best;
  __syncthreads();
  for (int st = 128; st > 0; st >>= 1) {
    if (t < st) red[t] = fmaxf(red[t], red[t + st]);
    __syncthreads();
  }
  if (t == 0) g_hpart[bid] = red[0];
}

// ---------------- K4 ----------------
__global__ __launch_bounds__(64) void fin_kernel(const float* __restrict__ g_hpart,
                                                 float* __restrict__ out) {
  const int t = threadIdx.x;  // one thread per image
  float mx = 0.0f;
  for (int j = 0; j < 8; ++j) mx = fmaxf(mx, g_hpart[t * 8 + j]);
  float diag = sqrtf((float)(HH * HH + WW * WW));
  float hd = sqrtf(fmaxf(mx, 0.0f)) / diag;
  hd = fminf(fmaxf(hd, 0.0f), 0.1f);
  float s = hd;
  for (int o = 32; o > 0; o >>= 1) s += __shfl_down(s, o);
  if (t == 0) out[0] = s * 0.015625f;
}

// ---------------- workspace layout (bytes) — nothing pre-zeroed ----------
#define WS_SCNT   0u                          // 2048*8 = 16384
#define WS_COUNTS 16384u                      // 512
#define WS_HPART  (WS_COUNTS + 512u)          // 2048
#define WS_PTS    (WS_HPART + 2048u)          // 512000
#define WS_CAND   (WS_PTS + 512000u)          // 2048*320*8 = 5242880  (~5.5 MB total)

extern "C" void kernel_launch(void* const* d_in, const int* in_sizes, int n_in,
                              void* d_out, int out_size, void* d_ws, size_t ws_size,
                              hipStream_t stream) {
  const float* pred = (const float*)d_in[0];
  const float* tgt = (const float*)d_in[1];
  float* out = (float*)d_out;
  char* ws = (char*)d_ws;
  int2* g_scnt = (int2*)(ws + WS_SCNT);
  int* g_counts = (int*)(ws + WS_COUNTS);
  float* g_hpart = (float*)(ws + WS_HPART);
  uint32_t* g_pts = (uint32_t*)(ws + WS_PTS);
  unsigned long long* g_cand = (unsigned long long*)(ws + WS_CAND);

  sobel_cand<<<2048, 256, 0, stream>>>(pred, tgt, g_scnt, g_cand);
  resolve_kernel<<<128, 256, 0, stream>>>(pred, tgt, g_scnt, g_cand, g_pts, g_counts);
  haus_kernel<<<512, 256, 0, stream>>>(g_pts, g_counts, g_hpart);
  fin_kernel<<<1, 64, 0, stream>>>(g_hpart, out);
}